// Round 9
// baseline (960.108 us; speedup 1.0000x reference)
//
#include <hip/hip_runtime.h>
#include <hip/hip_bf16.h>

using bf16 = __hip_bfloat16;
typedef __attribute__((ext_vector_type(8))) short bf16x8;
typedef __attribute__((ext_vector_type(4))) float f32x4;

constexpr int N_   = 16384;
constexpr int E_   = 262144;
constexpr int F_   = 16;
constexpr int H_   = 128;
constexpr int NFUSE_ = 1664; // q(512)|k(512)|v(512)|skip(128)
constexpr int DFF_ = 512;
constexpr int G_   = 128;
constexpr int L_   = 5;
constexpr float EPS_ = 1e-5f;

constexpr int WCATSZ = NFUSE_ * 128;   // 212992
constexpr int W1TSZ  = 512 * 128;      // 65536
constexpr int W2TSZ  = 512 * 128;      // 65536
constexpr int TRBLKS = 5 * 336;        // transpose blocks

__device__ __forceinline__ float gelu_f(float x) {
  return 0.5f * x * (1.0f + erff(x * 0.70710678118654752440f));
}

__device__ __forceinline__ void unpack8(const uint4 w, float* f) {
  f[0] = __uint_as_float(w.x << 16); f[1] = __uint_as_float(w.x & 0xFFFF0000u);
  f[2] = __uint_as_float(w.y << 16); f[3] = __uint_as_float(w.y & 0xFFFF0000u);
  f[4] = __uint_as_float(w.z << 16); f[5] = __uint_as_float(w.z & 0xFFFF0000u);
  f[6] = __uint_as_float(w.w << 16); f[7] = __uint_as_float(w.w & 0xFFFF0000u);
}

// ---------------- weight prep: LDS-tiled 32x32 transpose + bf16 cast + bias concat ----------------
__global__ __launch_bounds__(256) void k_ptrans(
    const float* __restrict__ Wq, const float* __restrict__ Wk,
    const float* __restrict__ Wv, const float* __restrict__ Ws,
    const float* __restrict__ W1, const float* __restrict__ W2,
    const float* __restrict__ bq, const float* __restrict__ bk,
    const float* __restrict__ bv, const float* __restrict__ bs,
    bf16* __restrict__ Wcat, bf16* __restrict__ W1t, bf16* __restrict__ W2t,
    float* __restrict__ bcat) {
  __shared__ float lds[32][33];
  const int b = blockIdx.x;
  if (b >= TRBLKS) {                 // bias-concat tail blocks
    int j = (b - TRBLKS) * 256 + threadIdx.x;
    if (j < 5 * NFUSE_) {
      int l = j / NFUSE_, c = j % NFUSE_;
      float v = (c < 512)  ? bq[l * 512 + c]
              : (c < 1024) ? bk[l * 512 + c - 512]
              : (c < 1536) ? bv[l * 512 + c - 1024]
              :              bs[l * 128 + c - 1536];
      bcat[j] = v;
    }
    return;
  }
  const int l = b / 336, t = b % 336;
  const float* src; int C; bf16* dst; int dld; int nof; int tt;
  if (t < 192) {        // Wq/Wk/Wv: [128][512] -> Wcat[n+off][kk]
    int which = t / 64; tt = t % 64;
    src = (which == 0 ? Wq : which == 1 ? Wk : Wv) + (size_t)l * 128 * 512;
    C = 512; dst = Wcat + (size_t)l * WCATSZ; dld = 128; nof = which * 512;
  } else if (t < 208) { // Ws: [128][128] -> Wcat[1536+n][kk]
    tt = t - 192;
    src = Ws + (size_t)l * 128 * 128; C = 128;
    dst = Wcat + (size_t)l * WCATSZ; dld = 128; nof = 1536;
  } else if (t < 272) { // W1: [128][512] -> W1t[n][kk] ld128
    tt = t - 208;
    src = W1 + (size_t)l * 128 * 512; C = 512;
    dst = W1t + (size_t)l * W1TSZ; dld = 128; nof = 0;
  } else {              // W2: [512][128] -> W2t[n][kk] ld512
    tt = t - 272;
    src = W2 + (size_t)l * 512 * 128; C = 128;
    dst = W2t + (size_t)l * W2TSZ; dld = 512; nof = 0;
  }
  const int tpr = C >> 5;
  const int r0 = (tt / tpr) * 32, c0 = (tt % tpr) * 32;
  const int j = threadIdx.x & 31, g = threadIdx.x >> 5;
#pragma unroll
  for (int ii = 0; ii < 4; ++ii) {
    int i = g * 4 + ii;
    lds[i][j] = src[(size_t)(r0 + i) * C + c0 + j];
  }
  __syncthreads();
#pragma unroll
  for (int ii = 0; ii < 4; ++ii) {
    int i = g * 4 + ii;
    dst[(size_t)(nof + c0 + i) * dld + r0 + j] = __float2bfloat16(lds[j][i]);
  }
}

// ---------------- embedding GEMM + fused BN partial stats ----------------
__global__ __launch_bounds__(256) void k_embed2(const float* __restrict__ x,
    const float* __restrict__ W, const float* __restrict__ b,
    float* __restrict__ out, float* __restrict__ ss, float* __restrict__ sq) {
  __shared__ float xs[128][16];
  __shared__ float wsm[16][128];
  __shared__ float sr[2][128], qr[2][128];
  const int blk = blockIdx.x;          // 128 blocks x 128 rows
  const int t = threadIdx.x;
  for (int i = t; i < 16 * 128; i += 256) wsm[i >> 7][i & 127] = W[i];
  for (int i = t; i < 128 * 16; i += 256) xs[i >> 4][i & 15] = x[(size_t)blk * 2048 + i];
  __syncthreads();
  const int c = t & 127, rg = t >> 7;
  float bc = b[c];
  float s = 0.f, q = 0.f;
  for (int r = rg * 64; r < rg * 64 + 64; ++r) {
    float v = bc;
#pragma unroll
    for (int f = 0; f < 16; ++f) v = fmaf(xs[r][f], wsm[f][c], v);
    out[(size_t)(blk * 128 + r) * 128 + c] = v;
    s += v; q += v * v;
  }
  sr[rg][c] = s; qr[rg][c] = q;
  __syncthreads();
  if (t < 128) { ss[blk * 128 + t] = sr[0][t] + sr[1][t]; sq[blk * 128 + t] = qr[0][t] + qr[1][t]; }
}

// ---------------- BatchNorm finalize / apply (embed path only) ----------------
template<int NC>
__global__ void k_bn_finalize(const float* __restrict__ sums, const float* __restrict__ sumsq,
                              const float* __restrict__ g, const float* __restrict__ be,
                              float* __restrict__ a, float* __restrict__ cc) {
  int c = blockIdx.x * 128 + threadIdx.x;
  if (c >= NC) return;
  float s = 0.f, q = 0.f;
  for (int b = 0; b < 128; ++b) { s += sums[b * NC + c]; q += sumsq[b * NC + c]; }
  float mean = s * (1.0f / N_);
  float var  = q * (1.0f / N_) - mean * mean;
  float inv  = rsqrtf(var + EPS_);
  float aa   = g[c] * inv;
  a[c]  = aa;
  cc[c] = be[c] - aa * mean;
}

template<int NC>
__global__ void k_bn_apply_gelu_cast(const float* __restrict__ xin, const float* __restrict__ a,
                                     const float* __restrict__ cc, bf16* __restrict__ outb) {
  int i4 = (blockIdx.x * 256 + threadIdx.x) * 4;
  int c = i4 & (NC - 1);
  float4 v = *reinterpret_cast<const float4*>(xin + i4);
  union { uint2 u2; bf16 h[4]; } pk;
  pk.h[0] = __float2bfloat16(gelu_f(fmaf(a[c + 0], v.x, cc[c + 0])));
  pk.h[1] = __float2bfloat16(gelu_f(fmaf(a[c + 1], v.y, cc[c + 1])));
  pk.h[2] = __float2bfloat16(gelu_f(fmaf(a[c + 2], v.z, cc[c + 2])));
  pk.h[3] = __float2bfloat16(gelu_f(fmaf(a[c + 3], v.w, cc[c + 3])));
  *reinterpret_cast<uint2*>(outb + i4) = pk.u2;
}

// ---------------- CSR build over dst ----------------
__global__ void k_count(const int* __restrict__ dst, int* __restrict__ deg) {
  int e = blockIdx.x * 256 + threadIdx.x;
  if (e < E_) atomicAdd(&deg[dst[e]], 1);
}

__global__ void k_bsum(const int* __restrict__ deg, int* __restrict__ bsum) {
  __shared__ int sh[256];
  int t = threadIdx.x;
  sh[t] = deg[blockIdx.x * 256 + t];
  __syncthreads();
  for (int d = 128; d > 0; d >>= 1) { if (t < d) sh[t] += sh[t + d]; __syncthreads(); }
  if (t == 0) bsum[blockIdx.x] = sh[0];
}

// block-level scan with inline top-level prefix over bsum (fused k_btop)
__global__ void k_boffs(const int* __restrict__ deg, const int* __restrict__ bsum,
                        int* __restrict__ offs) {
  __shared__ int sh[256];
  __shared__ int baseSh;
  int t = threadIdx.x;
  if (t < 64) {                       // wave 0: prefix over 64 block sums
    int v = bsum[t];
    int s = v;
    for (int d = 1; d < 64; d <<= 1) { int o = __shfl_up(s, d); if (t >= d) s += o; }
    if (t == (int)blockIdx.x) baseSh = s - v;   // exclusive prefix at this block
  }
  int v = deg[blockIdx.x * 256 + t];
  sh[t] = v;
  __syncthreads();
  for (int d = 1; d < 256; d <<= 1) {
    int add = (t >= d) ? sh[t - d] : 0;
    __syncthreads();
    sh[t] += add;
    __syncthreads();
  }
  offs[blockIdx.x * 256 + t] = baseSh + sh[t] - v;
  if (blockIdx.x == 63 && t == 255) offs[N_] = E_;
}

__global__ void k_scatter(const int* __restrict__ src, const int* __restrict__ dst,
                          const int* __restrict__ off, int* __restrict__ cursor,
                          int* __restrict__ srcs) {
  int e = blockIdx.x * 256 + threadIdx.x;
  if (e < E_) {
    int d = dst[e];
    int pos = off[d] + atomicAdd(&cursor[d], 1);
    srcs[pos] = src[e];
  }
}

// ---------------- bf16 MFMA GEMM: C[M,NOUT] = A[M,K] @ BT[NOUT,K]^T + bias ----------------
// MODE 2: fused qkv routing (Q fp32 / KV bf16 / xr fp32).
// MODE 3: fp32 out + per-m-tile BN column partial stats.
// MODE 4: A is FP32 pre-BN; prologue computes BN coeffs from stats (aCol=gamma, cCol=beta);
//         staging applies BN+GELU in fp32, casts bf16; fp32+bf16 out.
template<int KDIM, int NOUT, int TM, int MODE>
__global__ __launch_bounds__(256) void k_mfma(
    const bf16* __restrict__ A, const float* __restrict__ Af,
    const bf16* __restrict__ BT, const float* __restrict__ bias,
    float* __restrict__ outF, bf16* __restrict__ outB,
    float* __restrict__ Qfp, bf16* __restrict__ KVp, float* __restrict__ xrp,
    float* __restrict__ ss, float* __restrict__ sq,
    const float* __restrict__ aCol, const float* __restrict__ cCol) {
  constexpr int MF = TM / 32;
  __shared__ bf16 As[TM][72];
  __shared__ bf16 Bs[128][72];
  __shared__ float sred[2][128], qred[2][128];
  __shared__ float aS[MODE == 4 ? KDIM : 1], cS[MODE == 4 ? KDIM : 1];
  const int tid = threadIdx.x;
  const int wid = tid >> 6, lane = tid & 63;
  const int wr = wid >> 1, wc = wid & 1;
  const int m0 = blockIdx.x * TM, n0 = blockIdx.y * 128;
  const int ln = lane & 15, lq = lane >> 4;
  if constexpr (MODE == 4) {
    // fused bn_finalize: same op order as the standalone kernel -> identical values
    for (int c = tid; c < KDIM; c += 256) {
      float s = 0.f, q = 0.f;
      for (int b = 0; b < 128; ++b) { s += ss[b * KDIM + c]; q += sq[b * KDIM + c]; }
      float mean = s * (1.0f / N_);
      float var  = q * (1.0f / N_) - mean * mean;
      float inv  = rsqrtf(var + EPS_);
      float aa   = aCol[c] * inv;
      aS[c] = aa;
      cS[c] = cCol[c] - aa * mean;
    }
    __syncthreads();
  }
  f32x4 acc[MF][4];
#pragma unroll
  for (int i = 0; i < MF; ++i)
#pragma unroll
    for (int j = 0; j < 4; ++j) acc[i][j] = (f32x4){0.f, 0.f, 0.f, 0.f};

  for (int k0 = 0; k0 < KDIM; k0 += 64) {
#pragma unroll
    for (int u = tid; u < TM * 8; u += 256) {
      int r = u >> 3, c = u & 7;
      if constexpr (MODE == 4) {
        const float4* ap = reinterpret_cast<const float4*>(Af + (size_t)(m0 + r) * KDIM + k0 + c * 8);
        float4 f0 = ap[0], f1 = ap[1];
        float f[8] = {f0.x, f0.y, f0.z, f0.w, f1.x, f1.y, f1.z, f1.w};
        int colb = k0 + c * 8;
        union { uint4 u4; bf16 h[8]; } pk;
#pragma unroll
        for (int j = 0; j < 8; ++j)
          pk.h[j] = __float2bfloat16(gelu_f(fmaf(aS[colb + j], f[j], cS[colb + j])));
        *(uint4*)(&As[r][c * 8]) = pk.u4;
      } else {
        *(uint4*)(&As[r][c * 8]) = *(const uint4*)(A + (size_t)(m0 + r) * KDIM + k0 + c * 8);
      }
    }
#pragma unroll
    for (int u = tid; u < 1024; u += 256) {
      int r = u >> 3, c = u & 7;
      *(uint4*)(&Bs[r][c * 8]) = *(const uint4*)(BT + (size_t)(n0 + r) * KDIM + k0 + c * 8);
    }
    __syncthreads();
#pragma unroll
    for (int kk = 0; kk < 2; ++kk) {
      bf16x8 af[MF], bg[4];
#pragma unroll
      for (int i = 0; i < MF; ++i)
        af[i] = *(const bf16x8*)(&As[wr * (TM / 2) + i * 16 + ln][kk * 32 + lq * 8]);
#pragma unroll
      for (int j = 0; j < 4; ++j)
        bg[j] = *(const bf16x8*)(&Bs[wc * 64 + j * 16 + ln][kk * 32 + lq * 8]);
#pragma unroll
      for (int i = 0; i < MF; ++i)
#pragma unroll
        for (int j = 0; j < 4; ++j)
          acc[i][j] = __builtin_amdgcn_mfma_f32_16x16x32_bf16(af[i], bg[j], acc[i][j], 0, 0, 0);
    }
    __syncthreads();
  }
  float ssj[4] = {0.f, 0.f, 0.f, 0.f}, sqj[4] = {0.f, 0.f, 0.f, 0.f};
#pragma unroll
  for (int i = 0; i < MF; ++i) {
#pragma unroll
    for (int j = 0; j < 4; ++j) {
      int gcol = n0 + wc * 64 + j * 16 + ln;
      float bv = bias[gcol];
      int row0 = m0 + wr * (TM / 2) + i * 16 + lq * 4;
#pragma unroll
      for (int qq = 0; qq < 4; ++qq) {
        float val = acc[i][j][qq] + bv;
        int row = row0 + qq;
        if (MODE == 3) {
          outF[(size_t)row * NOUT + gcol] = val;
          ssj[j] += val; sqj[j] += val * val;
        } else if (MODE == 4) {
          outF[(size_t)row * NOUT + gcol] = val;
          outB[(size_t)row * NOUT + gcol] = __float2bfloat16(val);
        } else {
          if (n0 < 512)       Qfp[(size_t)row * 512 + gcol] = val;
          else if (n0 < 1536) KVp[(size_t)row * 1024 + (gcol - 512)] = __float2bfloat16(val);
          else                xrp[(size_t)row * H_ + (gcol - 1536)] = val;
        }
      }
    }
  }
  if constexpr (MODE == 3) {
#pragma unroll
    for (int j = 0; j < 4; ++j) {
      ssj[j] += __shfl_xor(ssj[j], 16); ssj[j] += __shfl_xor(ssj[j], 32);
      sqj[j] += __shfl_xor(sqj[j], 16); sqj[j] += __shfl_xor(sqj[j], 32);
    }
    if (lq == 0) {
#pragma unroll
      for (int j = 0; j < 4; ++j) {
        sred[wr][wc * 64 + j * 16 + ln] = ssj[j];
        qred[wr][wc * 64 + j * 16 + ln] = sqj[j];
      }
    }
    __syncthreads();
    if (tid < 128) {
      ss[(size_t)blockIdx.x * NOUT + n0 + tid] = sred[0][tid] + sred[1][tid];
      sq[(size_t)blockIdx.x * NOUT + n0 + tid] = qred[0][tid] + qred[1][tid];
    }
  }
}

// ---------------- fused attention + beta gate (one wave per dst node) ----------------
__global__ __launch_bounds__(256) void k_attn(const float* __restrict__ Qf,
    const bf16* __restrict__ KV, const float* __restrict__ xr,
    const float* __restrict__ Wb, const int* __restrict__ srcs,
    const int* __restrict__ off, bf16* __restrict__ gated) {
  const int wave = threadIdx.x >> 6;
  const int lane = threadIdx.x & 63;
  const int bid = blockIdx.x;                      // 4096 blocks
  const int swz = ((bid & 7) << 9) | (bid >> 3);   // XCD-contiguous 2048-node chunks
  const int node = swz * 4 + wave;
  const float scale = 0.08838834764831845f;        // 1/sqrt(128)
  float qf[8];
  {
    const float4* qp = reinterpret_cast<const float4*>(Qf + (size_t)node * 512) + lane * 2;
    float4 a = qp[0], b = qp[1];
    qf[0]=a.x; qf[1]=a.y; qf[2]=a.z; qf[3]=a.w;
    qf[4]=b.x; qf[5]=b.y; qf[6]=b.z; qf[7]=b.w;
  }
  float m = -1e30f, den = 0.f;
  float acc[8] = {0.f, 0.f, 0.f, 0.f, 0.f, 0.f, 0.f, 0.f};
  const int s0 = off[node], s1 = off[node + 1];
  if (s0 < s1) {
    int i0 = srcs[s0];
    int i1 = (s0 + 1 < s1) ? srcs[s0 + 1] : i0;
    const uint4* p0 = reinterpret_cast<const uint4*>(KV + (size_t)i0 * 1024) + lane;
    const uint4* p1 = reinterpret_cast<const uint4*>(KV + (size_t)i1 * 1024) + lane;
    uint4 k0 = p0[0], v0 = p0[64];
    uint4 k1 = p1[0], v1 = p1[64];
    for (int t = s0; t < s1; t += 2) {
      int j0 = (t + 2 < s1) ? srcs[t + 2] : i0;
      int j1 = (t + 3 < s1) ? srcs[t + 3] : i0;
      const uint4* q0 = reinterpret_cast<const uint4*>(KV + (size_t)j0 * 1024) + lane;
      const uint4* q1 = reinterpret_cast<const uint4*>(KV + (size_t)j1 * 1024) + lane;
      uint4 nk0 = q0[0], nv0 = q0[64];
      uint4 nk1 = q1[0], nv1 = q1[64];
      {
        float kf[8]; unpack8(k0, kf);
        float p = kf[0]*qf[0]+kf[1]*qf[1]+kf[2]*qf[2]+kf[3]*qf[3]
                + kf[4]*qf[4]+kf[5]*qf[5]+kf[6]*qf[6]+kf[7]*qf[7];
        p += __shfl_xor(p, 1); p += __shfl_xor(p, 2);
        p += __shfl_xor(p, 4); p += __shfl_xor(p, 8);
        float logit = p * scale;
        if (logit > m + 8.f) {
          float co = __expf(m - logit);
          den *= co;
#pragma unroll
          for (int j = 0; j < 8; ++j) acc[j] *= co;
          m = logit;
        }
        float pe = __expf(logit - m);
        den += pe;
        float vf[8]; unpack8(v0, vf);
#pragma unroll
        for (int j = 0; j < 8; ++j) acc[j] = fmaf(pe, vf[j], acc[j]);
      }
      if (t + 1 < s1) {
        float kf[8]; unpack8(k1, kf);
        float p = kf[0]*qf[0]+kf[1]*qf[1]+kf[2]*qf[2]+kf[3]*qf[3]
                + kf[4]*qf[4]+kf[5]*qf[5]+kf[6]*qf[6]+kf[7]*qf[7];
        p += __shfl_xor(p, 1); p += __shfl_xor(p, 2);
        p += __shfl_xor(p, 4); p += __shfl_xor(p, 8);
        float logit = p * scale;
        if (logit > m + 8.f) {
          float co = __expf(m - logit);
          den *= co;
#pragma unroll
          for (int j = 0; j < 8; ++j) acc[j] *= co;
          m = logit;
        }
        float pe = __expf(logit - m);
        den += pe;
        float vf[8]; unpack8(v1, vf);
#pragma unroll
        for (int j = 0; j < 8; ++j) acc[j] = fmaf(pe, vf[j], acc[j]);
      }
      k0 = nk0; v0 = nv0; k1 = nk1; v1 = nv1;
    }
  }
  float inv = 1.f / (den + 1e-16f);
  float r[8];
#pragma unroll
  for (int j = 0; j < 8; ++j) {
    r[j] = acc[j] * inv;
    r[j] += __shfl_xor(r[j], 16);
    r[j] += __shfl_xor(r[j], 32);
    r[j] *= 0.25f;                 // mean over 4 heads; all lanes hold result
  }
  const int c0 = (lane & 15) * 8;
  float xv[8];
  const float* xp = xr + (size_t)node * H_ + c0;
#pragma unroll
  for (int j = 0; j < 8; ++j) xv[j] = xp[j];
  float s = 0.f;
#pragma unroll
  for (int j = 0; j < 8; ++j) {
    int c = c0 + j;
    s += r[j] * (Wb[c] + Wb[256 + c]) + xv[j] * (Wb[128 + c] - Wb[256 + c]);
  }
  s += __shfl_xor(s, 1); s += __shfl_xor(s, 2);
  s += __shfl_xor(s, 4); s += __shfl_xor(s, 8);
  float beta = 1.f / (1.f + __expf(-s));
  if (lane < 16) {
    union { uint4 u4; bf16 h[8]; } pk;
#pragma unroll
    for (int j = 0; j < 8; ++j) pk.h[j] = __float2bfloat16(beta * xv[j] + (1.f - beta) * r[j]);
    *reinterpret_cast<uint4*>(gated + (size_t)node * H_ + c0) = pk.u4;
  }
}

// ---------------- fused segment max-pool + prediction (batch_index is sorted) ----------------
__global__ __launch_bounds__(256) void k_poolpred(const float* __restrict__ h,
    const int* __restrict__ batch, const float* __restrict__ predW,
    const float* __restrict__ predb, float* __restrict__ out) {
  __shared__ float cm[2][128];
  __shared__ int range[2];
  const int g = blockIdx.x, t = threadIdx.x;
  if (t < 2) {                      // lower_bound(g) and lower_bound(g+1)
    int target = g + t;
    int lo = 0, hi = N_;
    while (lo < hi) { int mid = (lo + hi) >> 1; if (batch[mid] < target) lo = mid + 1; else hi = mid; }
    range[t] = lo;
  }
  __syncthreads();
  const int lo = range[0], hi = range[1];
  const int c = t & 127, rg = t >> 7;
  float m = -3.402823466e+38f;
  for (int r = lo + rg; r < hi; r += 2) m = fmaxf(m, h[(size_t)r * H_ + c]);
  cm[rg][c] = m;
  __syncthreads();
  if (t < 64) {
    float m0 = fmaxf(cm[0][t], cm[1][t]);
    float m1 = fmaxf(cm[0][t + 64], cm[1][t + 64]);
    float s = m0 * predW[t] + m1 * predW[t + 64];
#pragma unroll
    for (int d = 1; d < 64; d <<= 1) s += __shfl_xor(s, d);
    if (t == 0) out[g] = s + predb[0];
  }
}

extern "C" void kernel_launch(void* const* d_in, const int* in_sizes, int n_in,
                              void* d_out, int out_size, void* d_ws, size_t ws_size,
                              hipStream_t stream) {
  const float* x      = (const float*)d_in[0];
  const int*   edge   = (const int*)d_in[1];
  const int*   esrc   = edge;
  const int*   edst   = edge + E_;
  const int*   batch  = (const int*)d_in[2];
  const float* embW   = (const float*)d_in[3];
  const float* embb   = (const float*)d_in[4];
  const float* emb_g  = (const float*)d_in[5];
  const float* emb_be = (const float*)d_in[6];
  const float* Wq     = (const float*)d_in[7];
  const float* bq     = (const float*)d_in[8];
  const float* Wk     = (const float*)d_in[9];
  const float* bk     = (const float*)d_in[10];
  const float* Wv     = (const float*)d_in[11];
  const float* bv     = (const float*)d_in[12];
  const float* Wskip  = (const float*)d_in[13];
  const float* bskip  = (const float*)d_in[14];
  const float* Wbeta  = (const float*)d_in[15];
  const float* W1     = (const float*)d_in[16];
  const float* b1     = (const float*)d_in[17];
  const float* g1     = (const float*)d_in[18];
  const float* be1    = (const float*)d_in[19];
  const float* W2     = (const float*)d_in[20];
  const float* b2     = (const float*)d_in[21];
  const float* predW  = (const float*)d_in[22];
  const float* predb  = (const float*)d_in[23];

  // ---- workspace layout ----
  float* ws = (float*)d_ws;
  size_t o = 0;
  auto alloc_f = [&](size_t n) { float* p = ws + o; o += n; return p; };
  float* h32   = alloc_f((size_t)N_ * H_);
  float* t1    = alloc_f((size_t)N_ * DFF_);     // FFN1 fp32 out (pre-BN)
  float* xr    = alloc_f((size_t)N_ * H_);
  float* Qf    = alloc_f((size_t)N_ * 512);
  float* stats = alloc_f(2 * 128 * DFF_);
  float* a_c   = alloc_f(DFF_);
  float* c_c   = alloc_f(DFF_);
  float* bcat  = alloc_f(5 * NFUSE_);
  bf16* bp = (bf16*)(ws + o);
  size_t ob = 0;
  auto alloc_b = [&](size_t n) { bf16* p = bp + ob; ob += n; return p; };
  bf16* KV   = alloc_b((size_t)N_ * 1024);
  bf16* hb   = alloc_b((size_t)N_ * H_);
  bf16* gated= alloc_b((size_t)N_ * H_);
  bf16* Wcat = alloc_b((size_t)5 * WCATSZ);
  bf16* W1t  = alloc_b((size_t)5 * W1TSZ);
  bf16* W2t  = alloc_b((size_t)5 * W2TSZ);
  int* deg    = (int*)(bp + ob);
  int* offs   = deg + N_;
  int* cursor = offs + N_ + 1;
  int* srcs   = cursor + N_;
  int* bsum   = srcs + E_;       // 64

  // ---- weight prep (tiled transpose + bias concat, one grid) ----
  k_ptrans<<<TRBLKS + (5 * NFUSE_ + 255) / 256, 256, 0, stream>>>(
      Wq, Wk, Wv, Wskip, W1, W2, bq, bk, bv, bskip, Wcat, W1t, W2t, bcat);

  // ---- CSR build (hierarchical scan, btop fused into boffs) ----
  hipMemsetAsync(deg, 0, N_ * sizeof(int), stream);
  hipMemsetAsync(cursor, 0, N_ * sizeof(int), stream);
  k_count  <<<E_ / 256, 256, 0, stream>>>(edst, deg);
  k_bsum   <<<64, 256, 0, stream>>>(deg, bsum);
  k_boffs  <<<64, 256, 0, stream>>>(deg, bsum, offs);
  k_scatter<<<E_ / 256, 256, 0, stream>>>(esrc, edst, offs, cursor, srcs);

  // ---- embedding (+fused stats) + BN + GELU -> bf16 ----
  k_embed2<<<128, 256, 0, stream>>>(x, embW, embb, t1, stats, stats + 128 * 128);
  k_bn_finalize<128><<<1, 128, 0, stream>>>(stats, stats + 128 * 128, emb_g, emb_be, a_c, c_c);
  k_bn_apply_gelu_cast<128><<<N_ * H_ / 1024, 256, 0, stream>>>(t1, a_c, c_c, hb);

  for (int l = 0; l < L_; ++l) {
    const float* Wb_ = Wbeta + (size_t)l * 3 * H_;
    const float* b1_ = b1 + (size_t)l * DFF_;
    const float* g1_ = g1 + (size_t)l * DFF_;
    const float* be1_= be1 + (size_t)l * DFF_;
    const float* b2_ = b2 + (size_t)l * H_;

    k_mfma<128, NFUSE_, 128, 2><<<dim3(N_ / 128, NFUSE_ / 128), 256, 0, stream>>>(
        hb, nullptr, Wcat + (size_t)l * WCATSZ, bcat + (size_t)l * NFUSE_,
        nullptr, nullptr, Qf, KV, xr, nullptr, nullptr, nullptr, nullptr);

    k_attn<<<N_ / 4, 256, 0, stream>>>(Qf, KV, xr, Wb_, srcs, offs, gated);

    // FFN1: fp32 out + fused BN partial stats
    k_mfma<128, 512, 128, 3><<<dim3(N_ / 128, 4), 256, 0, stream>>>(
        gated, nullptr, W1t + (size_t)l * W1TSZ, b1_, t1, nullptr, nullptr, nullptr, nullptr,
        stats, stats + 128 * 512, nullptr, nullptr);

    // FFN2: bn_finalize fused into prologue; BN+GELU fused into fp32 A-staging
    k_mfma<512, 128, 64, 4><<<dim3(N_ / 64, 1), 256, 0, stream>>>(
        nullptr, t1, W2t + (size_t)l * W2TSZ, b2_, h32, hb, nullptr, nullptr, nullptr,
        stats, stats + 128 * 512, g1_, be1_);
  }

  // ---- fused pooling + prediction ----
  k_poolpred<<<G_, 256, 0, stream>>>(h32, batch, predW, predb, (float*)d_out);
}

// Round 10
// 793.298 us; speedup vs baseline: 1.2103x; 1.2103x over previous
//
#include <hip/hip_runtime.h>
#include <hip/hip_bf16.h>

using bf16 = __hip_bfloat16;
typedef __attribute__((ext_vector_type(8))) short bf16x8;
typedef __attribute__((ext_vector_type(4))) float f32x4;

constexpr int N_   = 16384;
constexpr int E_   = 262144;
constexpr int F_   = 16;
constexpr int H_   = 128;
constexpr int NF2_ = 1152;   // z(512) | v(512) | skip(128)
constexpr int DFF_ = 512;
constexpr int G_   = 128;
constexpr int L_   = 5;
constexpr float EPS_ = 1e-5f;

constexpr int WCAT2SZ = NF2_ * 128;    // 147456
constexpr int W1TSZ   = 512 * 128;
constexpr int W2TSZ   = 512 * 128;
constexpr int TRBLKS  = 5 * 208;       // transpose blocks (v:64, s:16, w1:64, w2:64)

__device__ __forceinline__ float gelu_f(float x) {
  return 0.5f * x * (1.0f + erff(x * 0.70710678118654752440f));
}

__device__ __forceinline__ void unpack8(const uint4 w, float* f) {
  f[0] = __uint_as_float(w.x << 16); f[1] = __uint_as_float(w.x & 0xFFFF0000u);
  f[2] = __uint_as_float(w.y << 16); f[3] = __uint_as_float(w.y & 0xFFFF0000u);
  f[4] = __uint_as_float(w.z << 16); f[5] = __uint_as_float(w.z & 0xFFFF0000u);
  f[6] = __uint_as_float(w.w << 16); f[7] = __uint_as_float(w.w & 0xFFFF0000u);
}

// ---------------- weight prep: LDS-tiled 32x32 transpose + bf16 cast + bias concat ----------------
__global__ __launch_bounds__(256) void k_ptrans(
    const float* __restrict__ Wv, const float* __restrict__ Ws,
    const float* __restrict__ W1, const float* __restrict__ W2,
    const float* __restrict__ bv, const float* __restrict__ bs,
    bf16* __restrict__ Wcat2, bf16* __restrict__ W1t, bf16* __restrict__ W2t,
    float* __restrict__ bcat) {
  __shared__ float lds[32][33];
  const int b = blockIdx.x;
  if (b >= TRBLKS) {                 // bias-concat tail: only c >= 512 (z-bias by k_gmat)
    int j = (b - TRBLKS) * 256 + threadIdx.x;
    if (j < 5 * NF2_) {
      int l = j / NF2_, c = j % NF2_;
      if (c >= 512)
        bcat[j] = (c < 1024) ? bv[l * 512 + (c - 512)] : bs[l * 128 + (c - 1024)];
    }
    return;
  }
  const int l = b / 208, t = b % 208;
  const float* src; int C; bf16* dst; int dld; int nof; int tt;
  if (t < 64) {         // Wv: [128][512] -> Wcat2 rows 512..1023
    tt = t;
    src = Wv + (size_t)l * 128 * 512; C = 512;
    dst = Wcat2 + (size_t)l * WCAT2SZ; dld = 128; nof = 512;
  } else if (t < 80) {  // Ws: [128][128] -> Wcat2 rows 1024..1151
    tt = t - 64;
    src = Ws + (size_t)l * 128 * 128; C = 128;
    dst = Wcat2 + (size_t)l * WCAT2SZ; dld = 128; nof = 1024;
  } else if (t < 144) { // W1
    tt = t - 80;
    src = W1 + (size_t)l * 128 * 512; C = 512;
    dst = W1t + (size_t)l * W1TSZ; dld = 128; nof = 0;
  } else {              // W2
    tt = t - 144;
    src = W2 + (size_t)l * 512 * 128; C = 128;
    dst = W2t + (size_t)l * W2TSZ; dld = 512; nof = 0;
  }
  const int tpr = C >> 5;
  const int r0 = (tt / tpr) * 32, c0 = (tt % tpr) * 32;
  const int j = threadIdx.x & 31, g = threadIdx.x >> 5;
#pragma unroll
  for (int ii = 0; ii < 4; ++ii) {
    int i = g * 4 + ii;
    lds[i][j] = src[(size_t)(r0 + i) * C + c0 + j];
  }
  __syncthreads();
#pragma unroll
  for (int ii = 0; ii < 4; ++ii) {
    int i = g * 4 + ii;
    dst[(size_t)(nof + c0 + i) * dld + r0 + j] = __float2bfloat16(lds[j][i]);
  }
}

// ---------------- G = Wq_h @ Wk_h^T per (layer, head); writes GT rows of Wcat2 + z-bias ----------------
// grid (20, 2): block = (l*4+h, half). G[c,c'] = sum_a Wq[c,h*128+a] * Wk[c',h*128+a].
__global__ __launch_bounds__(256) void k_gmat(
    const float* __restrict__ Wq, const float* __restrict__ Wk,
    const float* __restrict__ bq,
    bf16* __restrict__ Wcat2, float* __restrict__ bcat) {
  __shared__ float lq[32][132];   // [a][c]
  __shared__ float lk[32][132];   // [a][c']
  const int l = blockIdx.x >> 2, h = blockIdx.x & 3;
  const int half = blockIdx.y;
  const int tid = threadIdx.x;
  const int c = tid & 127, ch = tid >> 7;
  const int cp0 = half * 64 + ch * 32;   // 32 c' per thread
  const float* wqL = Wq + (size_t)l * 128 * 512 + h * 128;
  const float* wkL = Wk + (size_t)l * 128 * 512 + h * 128;
  float acc[32];
#pragma unroll
  for (int j = 0; j < 32; ++j) acc[j] = 0.f;
  for (int a0 = 0; a0 < 128; a0 += 32) {
    __syncthreads();
#pragma unroll
    for (int q4 = 0; q4 < 4; ++q4) {
      int f4 = tid * 4 + q4;            // 0..1023
      int row = f4 >> 3, af = f4 & 7;   // row = c-index, af = float4 within a-chunk
      float4 gq = *reinterpret_cast<const float4*>(wqL + (size_t)row * 512 + a0 + af * 4);
      float4 gk = *reinterpret_cast<const float4*>(wkL + (size_t)row * 512 + a0 + af * 4);
      lq[af * 4 + 0][row] = gq.x; lq[af * 4 + 1][row] = gq.y;
      lq[af * 4 + 2][row] = gq.z; lq[af * 4 + 3][row] = gq.w;
      lk[af * 4 + 0][row] = gk.x; lk[af * 4 + 1][row] = gk.y;
      lk[af * 4 + 2][row] = gk.z; lk[af * 4 + 3][row] = gk.w;
    }
    __syncthreads();
    for (int a = 0; a < 32; ++a) {
      float wq = lq[a][c];
#pragma unroll
      for (int j = 0; j < 32; ++j) acc[j] = fmaf(wq, lk[a][cp0 + j], acc[j]);
    }
  }
  bf16* gt = Wcat2 + (size_t)l * WCAT2SZ;
#pragma unroll
  for (int j = 0; j < 32; ++j)
    gt[(size_t)(h * 128 + cp0 + j) * 128 + c] = __float2bfloat16(acc[j]);
  // exact bq handling: z-bias w_h[c'] = sum_a Wk[c',h*128+a] * bq[h*128+a]
  if (half == 0 && ch == 0) {
    float s = 0.f;
    const float* wkr = wkL + (size_t)c * 512;
    const float* bqh = bq + (size_t)l * 512 + h * 128;
    for (int a = 0; a < 128; ++a) s = fmaf(wkr[a], bqh[a], s);
    bcat[(size_t)l * NF2_ + h * 128 + c] = s;
  }
}

// ---------------- embedding GEMM + fused BN partial stats ----------------
__global__ __launch_bounds__(256) void k_embed2(const float* __restrict__ x,
    const float* __restrict__ W, const float* __restrict__ b,
    float* __restrict__ out, float* __restrict__ ss, float* __restrict__ sq) {
  __shared__ float xs[128][16];
  __shared__ float wsm[16][128];
  __shared__ float sr[2][128], qr[2][128];
  const int blk = blockIdx.x;
  const int t = threadIdx.x;
  for (int i = t; i < 16 * 128; i += 256) wsm[i >> 7][i & 127] = W[i];
  for (int i = t; i < 128 * 16; i += 256) xs[i >> 4][i & 15] = x[(size_t)blk * 2048 + i];
  __syncthreads();
  const int c = t & 127, rg = t >> 7;
  float bc = b[c];
  float s = 0.f, q = 0.f;
  for (int r = rg * 64; r < rg * 64 + 64; ++r) {
    float v = bc;
#pragma unroll
    for (int f = 0; f < 16; ++f) v = fmaf(xs[r][f], wsm[f][c], v);
    out[(size_t)(blk * 128 + r) * 128 + c] = v;
    s += v; q += v * v;
  }
  sr[rg][c] = s; qr[rg][c] = q;
  __syncthreads();
  if (t < 128) { ss[blk * 128 + t] = sr[0][t] + sr[1][t]; sq[blk * 128 + t] = qr[0][t] + qr[1][t]; }
}

// ---------------- BatchNorm finalize / apply ----------------
template<int NC>
__global__ void k_bn_finalize(const float* __restrict__ sums, const float* __restrict__ sumsq,
                              const float* __restrict__ g, const float* __restrict__ be,
                              float* __restrict__ a, float* __restrict__ cc) {
  int c = blockIdx.x * 128 + threadIdx.x;
  if (c >= NC) return;
  float s = 0.f, q = 0.f;
  for (int b = 0; b < 128; ++b) { s += sums[b * NC + c]; q += sumsq[b * NC + c]; }
  float mean = s * (1.0f / N_);
  float var  = q * (1.0f / N_) - mean * mean;
  float inv  = rsqrtf(var + EPS_);
  float aa   = g[c] * inv;
  a[c]  = aa;
  cc[c] = be[c] - aa * mean;
}

template<int NC>
__global__ void k_bn_apply_gelu_cast(const float* __restrict__ xin, const float* __restrict__ a,
                                     const float* __restrict__ cc, bf16* __restrict__ outb) {
  int i4 = (blockIdx.x * 256 + threadIdx.x) * 4;
  int c = i4 & (NC - 1);
  float4 v = *reinterpret_cast<const float4*>(xin + i4);
  union { uint2 u2; bf16 h[4]; } pk;
  pk.h[0] = __float2bfloat16(gelu_f(fmaf(a[c + 0], v.x, cc[c + 0])));
  pk.h[1] = __float2bfloat16(gelu_f(fmaf(a[c + 1], v.y, cc[c + 1])));
  pk.h[2] = __float2bfloat16(gelu_f(fmaf(a[c + 2], v.z, cc[c + 2])));
  pk.h[3] = __float2bfloat16(gelu_f(fmaf(a[c + 3], v.w, cc[c + 3])));
  *reinterpret_cast<uint2*>(outb + i4) = pk.u2;
}

// ---------------- CSR build over dst ----------------
__global__ void k_count(const int* __restrict__ dst, int* __restrict__ deg) {
  int e = blockIdx.x * 256 + threadIdx.x;
  if (e < E_) atomicAdd(&deg[dst[e]], 1);
}

__global__ void k_bsum(const int* __restrict__ deg, int* __restrict__ bsum) {
  __shared__ int sh[256];
  int t = threadIdx.x;
  sh[t] = deg[blockIdx.x * 256 + t];
  __syncthreads();
  for (int d = 128; d > 0; d >>= 1) { if (t < d) sh[t] += sh[t + d]; __syncthreads(); }
  if (t == 0) bsum[blockIdx.x] = sh[0];
}

__global__ void k_boffs(const int* __restrict__ deg, const int* __restrict__ bsum,
                        int* __restrict__ offs) {
  __shared__ int sh[256];
  __shared__ int baseSh;
  int t = threadIdx.x;
  if (t < 64) {
    int v = bsum[t];
    int s = v;
    for (int d = 1; d < 64; d <<= 1) { int o = __shfl_up(s, d); if (t >= d) s += o; }
    if (t == (int)blockIdx.x) baseSh = s - v;
  }
  int v = deg[blockIdx.x * 256 + t];
  sh[t] = v;
  __syncthreads();
  for (int d = 1; d < 256; d <<= 1) {
    int add = (t >= d) ? sh[t - d] : 0;
    __syncthreads();
    sh[t] += add;
    __syncthreads();
  }
  offs[blockIdx.x * 256 + t] = baseSh + sh[t] - v;
  if (blockIdx.x == 63 && t == 255) offs[N_] = E_;
}

__global__ void k_scatter(const int* __restrict__ src, const int* __restrict__ dst,
                          const int* __restrict__ off, int* __restrict__ cursor,
                          int* __restrict__ srcs) {
  int e = blockIdx.x * 256 + threadIdx.x;
  if (e < E_) {
    int d = dst[e];
    int pos = off[d] + atomicAdd(&cursor[d], 1);
    srcs[pos] = src[e];
  }
}

// ---------------- bf16 MFMA GEMM ----------------
// MODE 2: fused routing: z fp32 (cols<512) / V bf16 (<1024) / xr fp32.
// MODE 3: fp32 out + per-m-tile BN column partial stats.
// MODE 4: A fp32 pre-BN; staging applies BN(a,c)+GELU, casts bf16; fp32+bf16 out.
template<int KDIM, int NOUT, int TM, int MODE>
__global__ __launch_bounds__(256) void k_mfma(
    const bf16* __restrict__ A, const float* __restrict__ Af,
    const bf16* __restrict__ BT, const float* __restrict__ bias,
    float* __restrict__ outF, bf16* __restrict__ outB,
    float* __restrict__ zfp, bf16* __restrict__ Vpp, float* __restrict__ xrp,
    float* __restrict__ ss, float* __restrict__ sq,
    const float* __restrict__ aCol, const float* __restrict__ cCol) {
  constexpr int MF = TM / 32;
  __shared__ bf16 As[TM][72];
  __shared__ bf16 Bs[128][72];
  __shared__ float sred[2][128], qred[2][128];
  __shared__ float aS[MODE == 4 ? KDIM : 1], cS[MODE == 4 ? KDIM : 1];
  const int tid = threadIdx.x;
  const int wid = tid >> 6, lane = tid & 63;
  const int wr = wid >> 1, wc = wid & 1;
  const int m0 = blockIdx.x * TM, n0 = blockIdx.y * 128;
  const int ln = lane & 15, lq = lane >> 4;
  if constexpr (MODE == 4) {
    for (int i = tid; i < KDIM; i += 256) { aS[i] = aCol[i]; cS[i] = cCol[i]; }
    __syncthreads();
  }
  f32x4 acc[MF][4];
#pragma unroll
  for (int i = 0; i < MF; ++i)
#pragma unroll
    for (int j = 0; j < 4; ++j) acc[i][j] = (f32x4){0.f, 0.f, 0.f, 0.f};

  for (int k0 = 0; k0 < KDIM; k0 += 64) {
#pragma unroll
    for (int u = tid; u < TM * 8; u += 256) {
      int r = u >> 3, c = u & 7;
      if constexpr (MODE == 4) {
        const float4* ap = reinterpret_cast<const float4*>(Af + (size_t)(m0 + r) * KDIM + k0 + c * 8);
        float4 f0 = ap[0], f1 = ap[1];
        float f[8] = {f0.x, f0.y, f0.z, f0.w, f1.x, f1.y, f1.z, f1.w};
        int colb = k0 + c * 8;
        union { uint4 u4; bf16 h[8]; } pk;
#pragma unroll
        for (int j = 0; j < 8; ++j)
          pk.h[j] = __float2bfloat16(gelu_f(fmaf(aS[colb + j], f[j], cS[colb + j])));
        *(uint4*)(&As[r][c * 8]) = pk.u4;
      } else {
        *(uint4*)(&As[r][c * 8]) = *(const uint4*)(A + (size_t)(m0 + r) * KDIM + k0 + c * 8);
      }
    }
#pragma unroll
    for (int u = tid; u < 1024; u += 256) {
      int r = u >> 3, c = u & 7;
      *(uint4*)(&Bs[r][c * 8]) = *(const uint4*)(BT + (size_t)(n0 + r) * KDIM + k0 + c * 8);
    }
    __syncthreads();
#pragma unroll
    for (int kk = 0; kk < 2; ++kk) {
      bf16x8 af[MF], bg[4];
#pragma unroll
      for (int i = 0; i < MF; ++i)
        af[i] = *(const bf16x8*)(&As[wr * (TM / 2) + i * 16 + ln][kk * 32 + lq * 8]);
#pragma unroll
      for (int j = 0; j < 4; ++j)
        bg[j] = *(const bf16x8*)(&Bs[wc * 64 + j * 16 + ln][kk * 32 + lq * 8]);
#pragma unroll
      for (int i = 0; i < MF; ++i)
#pragma unroll
        for (int j = 0; j < 4; ++j)
          acc[i][j] = __builtin_amdgcn_mfma_f32_16x16x32_bf16(af[i], bg[j], acc[i][j], 0, 0, 0);
    }
    __syncthreads();
  }
  float ssj[4] = {0.f, 0.f, 0.f, 0.f}, sqj[4] = {0.f, 0.f, 0.f, 0.f};
#pragma unroll
  for (int i = 0; i < MF; ++i) {
#pragma unroll
    for (int j = 0; j < 4; ++j) {
      int gcol = n0 + wc * 64 + j * 16 + ln;
      float bv = bias[gcol];
      int row0 = m0 + wr * (TM / 2) + i * 16 + lq * 4;
#pragma unroll
      for (int qq = 0; qq < 4; ++qq) {
        float val = acc[i][j][qq] + bv;
        int row = row0 + qq;
        if (MODE == 3) {
          outF[(size_t)row * NOUT + gcol] = val;
          ssj[j] += val; sqj[j] += val * val;
        } else if (MODE == 4) {
          outF[(size_t)row * NOUT + gcol] = val;
          outB[(size_t)row * NOUT + gcol] = __float2bfloat16(val);
        } else {
          if (n0 < 512)       zfp[(size_t)row * 512 + gcol] = val;
          else if (n0 < 1024) Vpp[(size_t)row * 512 + (gcol - 512)] = __float2bfloat16(val);
          else                xrp[(size_t)row * H_ + (gcol - 1024)] = val;
        }
      }
    }
  }
  if constexpr (MODE == 3) {
#pragma unroll
    for (int j = 0; j < 4; ++j) {
      ssj[j] += __shfl_xor(ssj[j], 16); ssj[j] += __shfl_xor(ssj[j], 32);
      sqj[j] += __shfl_xor(sqj[j], 16); sqj[j] += __shfl_xor(sqj[j], 32);
    }
    if (lq == 0) {
#pragma unroll
      for (int j = 0; j < 4; ++j) {
        sred[wr][wc * 64 + j * 16 + ln] = ssj[j];
        qred[wr][wc * 64 + j * 16 + ln] = sqj[j];
      }
    }
    __syncthreads();
    if (tid < 128) {
      ss[(size_t)blockIdx.x * NOUT + n0 + tid] = sred[0][tid] + sred[1][tid];
      sq[(size_t)blockIdx.x * NOUT + n0 + tid] = qred[0][tid] + qred[1][tid];
    }
  }
}

// ---------------- fused attention + beta gate (one wave per dst node) ----------------
// logit_h = z[n, h*128+:] . hb[src, :]  (bilinear-form trick; K never materialized)
__global__ __launch_bounds__(256) void k_attn(const float* __restrict__ zf,
    const bf16* __restrict__ hb, const bf16* __restrict__ Vp,
    const float* __restrict__ xr, const float* __restrict__ Wb,
    const int* __restrict__ srcs, const int* __restrict__ off,
    bf16* __restrict__ gated) {
  const int wave = threadIdx.x >> 6;
  const int lane = threadIdx.x & 63;
  const int bid = blockIdx.x;                      // 4096 blocks
  const int swz = ((bid & 7) << 9) | (bid >> 3);   // XCD-contiguous 2048-node chunks
  const int node = swz * 4 + wave;
  const int sub = lane & 15;
  const float scale = 0.08838834764831845f;        // 1/sqrt(128)
  float qf[8];
  {
    const float4* qp = reinterpret_cast<const float4*>(zf + (size_t)node * 512) + lane * 2;
    float4 a = qp[0], b = qp[1];
    qf[0]=a.x; qf[1]=a.y; qf[2]=a.z; qf[3]=a.w;
    qf[4]=b.x; qf[5]=b.y; qf[6]=b.z; qf[7]=b.w;
  }
  float m = -1e30f, den = 0.f;
  float acc[8] = {0.f, 0.f, 0.f, 0.f, 0.f, 0.f, 0.f, 0.f};
  const int s0 = off[node], s1 = off[node + 1];
  if (s0 < s1) {
    int i0 = srcs[s0];
    int i1 = (s0 + 1 < s1) ? srcs[s0 + 1] : i0;
    uint4 h0 = *(const uint4*)(hb + (size_t)i0 * 128 + sub * 8);
    uint4 v0 = *(const uint4*)(Vp + (size_t)i0 * 512 + lane * 8);
    uint4 h1 = *(const uint4*)(hb + (size_t)i1 * 128 + sub * 8);
    uint4 v1 = *(const uint4*)(Vp + (size_t)i1 * 512 + lane * 8);
    for (int t = s0; t < s1; t += 2) {
      int j0 = (t + 2 < s1) ? srcs[t + 2] : i0;
      int j1 = (t + 3 < s1) ? srcs[t + 3] : i0;
      uint4 nh0 = *(const uint4*)(hb + (size_t)j0 * 128 + sub * 8);
      uint4 nv0 = *(const uint4*)(Vp + (size_t)j0 * 512 + lane * 8);
      uint4 nh1 = *(const uint4*)(hb + (size_t)j1 * 128 + sub * 8);
      uint4 nv1 = *(const uint4*)(Vp + (size_t)j1 * 512 + lane * 8);
      {
        float hf[8]; unpack8(h0, hf);
        float p = hf[0]*qf[0]+hf[1]*qf[1]+hf[2]*qf[2]+hf[3]*qf[3]
                + hf[4]*qf[4]+hf[5]*qf[5]+hf[6]*qf[6]+hf[7]*qf[7];
        p += __shfl_xor(p, 1); p += __shfl_xor(p, 2);
        p += __shfl_xor(p, 4); p += __shfl_xor(p, 8);
        float logit = p * scale;
        if (logit > m + 8.f) {
          float co = __expf(m - logit);
          den *= co;
#pragma unroll
          for (int j = 0; j < 8; ++j) acc[j] *= co;
          m = logit;
        }
        float pe = __expf(logit - m);
        den += pe;
        float vf[8]; unpack8(v0, vf);
#pragma unroll
        for (int j = 0; j < 8; ++j) acc[j] = fmaf(pe, vf[j], acc[j]);
      }
      if (t + 1 < s1) {
        float hf[8]; unpack8(h1, hf);
        float p = hf[0]*qf[0]+hf[1]*qf[1]+hf[2]*qf[2]+hf[3]*qf[3]
                + hf[4]*qf[4]+hf[5]*qf[5]+hf[6]*qf[6]+hf[7]*qf[7];
        p += __shfl_xor(p, 1); p += __shfl_xor(p, 2);
        p += __shfl_xor(p, 4); p += __shfl_xor(p, 8);
        float logit = p * scale;
        if (logit > m + 8.f) {
          float co = __expf(m - logit);
          den *= co;
#pragma unroll
          for (int j = 0; j < 8; ++j) acc[j] *= co;
          m = logit;
        }
        float pe = __expf(logit - m);
        den += pe;
        float vf[8]; unpack8(v1, vf);
#pragma unroll
        for (int j = 0; j < 8; ++j) acc[j] = fmaf(pe, vf[j], acc[j]);
      }
      h0 = nh0; v0 = nv0; h1 = nh1; v1 = nv1;
    }
  }
  float inv = 1.f / (den + 1e-16f);
  float r[8];
#pragma unroll
  for (int j = 0; j < 8; ++j) {
    r[j] = acc[j] * inv;
    r[j] += __shfl_xor(r[j], 16);
    r[j] += __shfl_xor(r[j], 32);
    r[j] *= 0.25f;                 // mean over 4 heads
  }
  const int c0 = sub * 8;
  float xv[8];
  const float* xp = xr + (size_t)node * H_ + c0;
#pragma unroll
  for (int j = 0; j < 8; ++j) xv[j] = xp[j];
  float s = 0.f;
#pragma unroll
  for (int j = 0; j < 8; ++j) {
    int c = c0 + j;
    s += r[j] * (Wb[c] + Wb[256 + c]) + xv[j] * (Wb[128 + c] - Wb[256 + c]);
  }
  s += __shfl_xor(s, 1); s += __shfl_xor(s, 2);
  s += __shfl_xor(s, 4); s += __shfl_xor(s, 8);
  float beta = 1.f / (1.f + __expf(-s));
  if (lane < 16) {
    union { uint4 u4; bf16 h[8]; } pk;
#pragma unroll
    for (int j = 0; j < 8; ++j) pk.h[j] = __float2bfloat16(beta * xv[j] + (1.f - beta) * r[j]);
    *reinterpret_cast<uint4*>(gated + (size_t)node * H_ + c0) = pk.u4;
  }
}

// ---------------- fused segment max-pool + prediction (batch_index is sorted) ----------------
__global__ __launch_bounds__(256) void k_poolpred(const float* __restrict__ h,
    const int* __restrict__ batch, const float* __restrict__ predW,
    const float* __restrict__ predb, float* __restrict__ out) {
  __shared__ float cm[2][128];
  __shared__ int range[2];
  const int g = blockIdx.x, t = threadIdx.x;
  if (t < 2) {
    int target = g + t;
    int lo = 0, hi = N_;
    while (lo < hi) { int mid = (lo + hi) >> 1; if (batch[mid] < target) lo = mid + 1; else hi = mid; }
    range[t] = lo;
  }
  __syncthreads();
  const int lo = range[0], hi = range[1];
  const int c = t & 127, rg = t >> 7;
  float m = -3.402823466e+38f;
  for (int r = lo + rg; r < hi; r += 2) m = fmaxf(m, h[(size_t)r * H_ + c]);
  cm[rg][c] = m;
  __syncthreads();
  if (t < 64) {
    float m0 = fmaxf(cm[0][t], cm[1][t]);
    float m1 = fmaxf(cm[0][t + 64], cm[1][t + 64]);
    float s = m0 * predW[t] + m1 * predW[t + 64];
#pragma unroll
    for (int d = 1; d < 64; d <<= 1) s += __shfl_xor(s, d);
    if (t == 0) out[g] = s + predb[0];
  }
}

extern "C" void kernel_launch(void* const* d_in, const int* in_sizes, int n_in,
                              void* d_out, int out_size, void* d_ws, size_t ws_size,
                              hipStream_t stream) {
  const float* x      = (const float*)d_in[0];
  const int*   edge   = (const int*)d_in[1];
  const int*   esrc   = edge;
  const int*   edst   = edge + E_;
  const int*   batch  = (const int*)d_in[2];
  const float* embW   = (const float*)d_in[3];
  const float* embb   = (const float*)d_in[4];
  const float* emb_g  = (const float*)d_in[5];
  const float* emb_be = (const float*)d_in[6];
  const float* Wq     = (const float*)d_in[7];
  const float* bq     = (const float*)d_in[8];
  const float* Wk     = (const float*)d_in[9];
  const float* bk     = (const float*)d_in[10];  // unused: bk terms are softmax-invariant
  const float* Wv     = (const float*)d_in[11];
  const float* bv     = (const float*)d_in[12];
  const float* Wskip  = (const float*)d_in[13];
  const float* bskip  = (const float*)d_in[14];
  const float* Wbeta  = (const float*)d_in[15];
  const float* W1     = (const float*)d_in[16];
  const float* b1     = (const float*)d_in[17];
  const float* g1     = (const float*)d_in[18];
  const float* be1    = (const float*)d_in[19];
  const float* W2     = (const float*)d_in[20];
  const float* b2     = (const float*)d_in[21];
  const float* predW  = (const float*)d_in[22];
  const float* predb  = (const float*)d_in[23];
  (void)bk;

  // ---- workspace layout ----
  float* ws = (float*)d_ws;
  size_t o = 0;
  auto alloc_f = [&](size_t n) { float* p = ws + o; o += n; return p; };
  float* h32   = alloc_f((size_t)N_ * H_);
  float* t1    = alloc_f((size_t)N_ * DFF_);     // FFN1 fp32 out (pre-BN)
  float* xr    = alloc_f((size_t)N_ * H_);
  float* zf    = alloc_f((size_t)N_ * 512);      // z = hb @ G (fp32)
  float* stats = alloc_f(2 * 128 * DFF_);
  float* a_c   = alloc_f(DFF_);
  float* c_c   = alloc_f(DFF_);
  float* bcat  = alloc_f(5 * NF2_);
  bf16* bp = (bf16*)(ws + o);
  size_t ob = 0;
  auto alloc_b = [&](size_t n) { bf16* p = bp + ob; ob += n; return p; };
  bf16* Vp   = alloc_b((size_t)N_ * 512);
  bf16* hb   = alloc_b((size_t)N_ * H_);
  bf16* gated= alloc_b((size_t)N_ * H_);
  bf16* Wcat2= alloc_b((size_t)5 * WCAT2SZ);
  bf16* W1t  = alloc_b((size_t)5 * W1TSZ);
  bf16* W2t  = alloc_b((size_t)5 * W2TSZ);
  int* deg    = (int*)(bp + ob);
  int* offs   = deg + N_;
  int* cursor = offs + N_ + 1;
  int* srcs   = cursor + N_;
  int* bsum   = srcs + E_;       // 64

  // ---- weight prep: transposes + bias tail, then G-matrices ----
  k_ptrans<<<TRBLKS + (5 * NF2_ + 255) / 256, 256, 0, stream>>>(
      Wv, Wskip, W1, W2, bv, bskip, Wcat2, W1t, W2t, bcat);
  k_gmat<<<dim3(20, 2), 256, 0, stream>>>(Wq, Wk, bq, Wcat2, bcat);

  // ---- CSR build ----
  hipMemsetAsync(deg, 0, N_ * sizeof(int), stream);
  hipMemsetAsync(cursor, 0, N_ * sizeof(int), stream);
  k_count  <<<E_ / 256, 256, 0, stream>>>(edst, deg);
  k_bsum   <<<64, 256, 0, stream>>>(deg, bsum);
  k_boffs  <<<64, 256, 0, stream>>>(deg, bsum, offs);
  k_scatter<<<E_ / 256, 256, 0, stream>>>(esrc, edst, offs, cursor, srcs);

  // ---- embedding (+fused stats) + BN + GELU -> bf16 ----
  k_embed2<<<128, 256, 0, stream>>>(x, embW, embb, t1, stats, stats + 128 * 128);
  k_bn_finalize<128><<<1, 128, 0, stream>>>(stats, stats + 128 * 128, emb_g, emb_be, a_c, c_c);
  k_bn_apply_gelu_cast<128><<<N_ * H_ / 1024, 256, 0, stream>>>(t1, a_c, c_c, hb);

  for (int l = 0; l < L_; ++l) {
    const float* Wb_ = Wbeta + (size_t)l * 3 * H_;
    const float* b1_ = b1 + (size_t)l * DFF_;
    const float* g1_ = g1 + (size_t)l * DFF_;
    const float* be1_= be1 + (size_t)l * DFF_;
    const float* b2_ = b2 + (size_t)l * H_;

    // z | V | xr fused GEMM (NOUT = 1152)
    k_mfma<128, NF2_, 128, 2><<<dim3(N_ / 128, NF2_ / 128), 256, 0, stream>>>(
        hb, nullptr, Wcat2 + (size_t)l * WCAT2SZ, bcat + (size_t)l * NF2_,
        nullptr, nullptr, zf, Vp, xr, nullptr, nullptr, nullptr, nullptr);

    k_attn<<<N_ / 4, 256, 0, stream>>>(zf, hb, Vp, xr, Wb_, srcs, offs, gated);

    // FFN1: fp32 out + fused BN partial stats
    k_mfma<128, 512, 128, 3><<<dim3(N_ / 128, 4), 256, 0, stream>>>(
        gated, nullptr, W1t + (size_t)l * W1TSZ, b1_, t1, nullptr, nullptr, nullptr, nullptr,
        stats, stats + 128 * 512, nullptr, nullptr);

    k_bn_finalize<512><<<4, 128, 0, stream>>>(stats, stats + 128 * 512, g1_, be1_, a_c, c_c);

    // FFN2: BN+GELU fused into fp32 A-staging
    k_mfma<512, 128, 64, 4><<<dim3(N_ / 64, 1), 256, 0, stream>>>(
        nullptr, t1, W2t + (size_t)l * W2TSZ, b2_, h32, hb, nullptr, nullptr, nullptr,
        nullptr, nullptr, a_c, c_c);
  }

  // ---- fused pooling + prediction ----
  k_poolpred<<<G_, 256, 0, stream>>>(h32, batch, predW, predb, (float*)d_out);
}

// Round 11
// 765.813 us; speedup vs baseline: 1.2537x; 1.0359x over previous
//
#include <hip/hip_runtime.h>
#include <hip/hip_bf16.h>

using bf16 = __hip_bfloat16;
typedef __attribute__((ext_vector_type(8))) short bf16x8;
typedef __attribute__((ext_vector_type(4))) float f32x4;

constexpr int N_   = 16384;
constexpr int E_   = 262144;
constexpr int F_   = 16;
constexpr int H_   = 128;
constexpr int NF1_ = 640;    // z(512) | skip(128)
constexpr int DFF_ = 512;
constexpr int G_   = 128;
constexpr int L_   = 5;
constexpr float EPS_ = 1e-5f;

constexpr int WCAT1SZ = NF1_ * 128;    // 81920
constexpr int W1TSZ   = 512 * 128;
constexpr int W2TSZ   = 512 * 128;
constexpr int WVSSZ   = 128 * 512;     // Wvs: [128 n][512 k]
constexpr int TRBLKS  = 5 * 144;       // Ws:16 + W1:64 + W2:64 per layer

__device__ __forceinline__ float gelu_f(float x) {
  return 0.5f * x * (1.0f + erff(x * 0.70710678118654752440f));
}

__device__ __forceinline__ void unpack8(const uint4 w, float* f) {
  f[0] = __uint_as_float(w.x << 16); f[1] = __uint_as_float(w.x & 0xFFFF0000u);
  f[2] = __uint_as_float(w.y << 16); f[3] = __uint_as_float(w.y & 0xFFFF0000u);
  f[4] = __uint_as_float(w.z << 16); f[5] = __uint_as_float(w.z & 0xFFFF0000u);
  f[6] = __uint_as_float(w.w << 16); f[7] = __uint_as_float(w.w & 0xFFFF0000u);
}

// ---------------- weight prep: transposes (Ws,W1,W2) + bias tails ----------------
__global__ __launch_bounds__(256) void k_ptrans(
    const float* __restrict__ Ws, const float* __restrict__ W1,
    const float* __restrict__ W2, const float* __restrict__ bs,
    const float* __restrict__ bv,
    bf16* __restrict__ Wcat1, bf16* __restrict__ W1t, bf16* __restrict__ W2t,
    float* __restrict__ bcat, float* __restrict__ bvm) {
  __shared__ float lds[32][33];
  const int b = blockIdx.x;
  if (b >= TRBLKS) {                 // tails: bcat skip-cols + bvm
    int j = (b - TRBLKS) * 256 + threadIdx.x;
    if (j < 5 * NF1_) {
      int l = j / NF1_, c = j % NF1_;
      if (c >= 512) bcat[j] = bs[l * 128 + (c - 512)];
    } else if (j < 5 * NF1_ + 5 * 128) {
      int j2 = j - 5 * NF1_;
      int l = j2 / 128, n = j2 % 128;
      bvm[j2] = 0.25f * (bv[l * 512 + n] + bv[l * 512 + 128 + n]
                       + bv[l * 512 + 256 + n] + bv[l * 512 + 384 + n]);
    }
    return;
  }
  const int l = b / 144, t = b % 144;
  const float* src; int C; bf16* dst; int dld; int nof; int tt;
  if (t < 16) {         // Ws: [128][128] -> Wcat1 rows 512..639
    tt = t;
    src = Ws + (size_t)l * 128 * 128; C = 128;
    dst = Wcat1 + (size_t)l * WCAT1SZ; dld = 128; nof = 512;
  } else if (t < 80) {  // W1
    tt = t - 16;
    src = W1 + (size_t)l * 128 * 512; C = 512;
    dst = W1t + (size_t)l * W1TSZ; dld = 128; nof = 0;
  } else {              // W2
    tt = t - 80;
    src = W2 + (size_t)l * 512 * 128; C = 128;
    dst = W2t + (size_t)l * W2TSZ; dld = 512; nof = 0;
  }
  const int tpr = C >> 5;
  const int r0 = (tt / tpr) * 32, c0 = (tt % tpr) * 32;
  const int j = threadIdx.x & 31, g = threadIdx.x >> 5;
#pragma unroll
  for (int ii = 0; ii < 4; ++ii) {
    int i = g * 4 + ii;
    lds[i][j] = src[(size_t)(r0 + i) * C + c0 + j];
  }
  __syncthreads();
#pragma unroll
  for (int ii = 0; ii < 4; ++ii) {
    int i = g * 4 + ii;
    dst[(size_t)(nof + c0 + i) * dld + r0 + j] = __float2bfloat16(lds[j][i]);
  }
}

// ---------------- Wvs: per head, Wvs[n][h*128+c] = 0.25 * Wv[c][h*128+n] ----------------
__global__ __launch_bounds__(256) void k_wvprep(const float* __restrict__ Wv,
                                                bf16* __restrict__ Wvs) {
  __shared__ float lds[32][33];
  const int b = blockIdx.x;            // 5*4*16
  const int l = b / 64, rest = b % 64;
  const int h = rest / 16, tt = rest % 16;
  const int r0 = (tt / 4) * 32, c0 = (tt % 4) * 32;  // r0: c-block, c0: n-block
  const float* src = Wv + (size_t)l * 128 * 512 + h * 128;
  bf16* dst = Wvs + (size_t)l * WVSSZ;
  const int j = threadIdx.x & 31, g = threadIdx.x >> 5;
#pragma unroll
  for (int ii = 0; ii < 4; ++ii) {
    int i = g * 4 + ii;
    lds[i][j] = src[(size_t)(r0 + i) * 512 + c0 + j];
  }
  __syncthreads();
#pragma unroll
  for (int ii = 0; ii < 4; ++ii) {
    int i = g * 4 + ii;
    dst[(size_t)(c0 + i) * 512 + h * 128 + r0 + j] = __float2bfloat16(0.25f * lds[j][i]);
  }
}

// ---------------- G = Wq_h @ Wk_h^T per (layer, head); writes GT rows + z-bias ----------------
__global__ __launch_bounds__(256) void k_gmat(
    const float* __restrict__ Wq, const float* __restrict__ Wk,
    const float* __restrict__ bq,
    bf16* __restrict__ Wcat1, float* __restrict__ bcat) {
  __shared__ float lq[32][132];
  __shared__ float lk[32][132];
  const int l = blockIdx.x >> 2, h = blockIdx.x & 3;
  const int half = blockIdx.y;
  const int tid = threadIdx.x;
  const int c = tid & 127, ch = tid >> 7;
  const int cp0 = half * 64 + ch * 32;
  const float* wqL = Wq + (size_t)l * 128 * 512 + h * 128;
  const float* wkL = Wk + (size_t)l * 128 * 512 + h * 128;
  float acc[32];
#pragma unroll
  for (int j = 0; j < 32; ++j) acc[j] = 0.f;
  for (int a0 = 0; a0 < 128; a0 += 32) {
    __syncthreads();
#pragma unroll
    for (int q4 = 0; q4 < 4; ++q4) {
      int f4 = tid * 4 + q4;
      int row = f4 >> 3, af = f4 & 7;
      float4 gq = *reinterpret_cast<const float4*>(wqL + (size_t)row * 512 + a0 + af * 4);
      float4 gk = *reinterpret_cast<const float4*>(wkL + (size_t)row * 512 + a0 + af * 4);
      lq[af * 4 + 0][row] = gq.x; lq[af * 4 + 1][row] = gq.y;
      lq[af * 4 + 2][row] = gq.z; lq[af * 4 + 3][row] = gq.w;
      lk[af * 4 + 0][row] = gk.x; lk[af * 4 + 1][row] = gk.y;
      lk[af * 4 + 2][row] = gk.z; lk[af * 4 + 3][row] = gk.w;
    }
    __syncthreads();
    for (int a = 0; a < 32; ++a) {
      float wq = lq[a][c];
#pragma unroll
      for (int j = 0; j < 32; ++j) acc[j] = fmaf(wq, lk[a][cp0 + j], acc[j]);
    }
  }
  bf16* gt = Wcat1 + (size_t)l * WCAT1SZ;
#pragma unroll
  for (int j = 0; j < 32; ++j)
    gt[(size_t)(h * 128 + cp0 + j) * 128 + c] = __float2bfloat16(acc[j]);
  if (half == 0 && ch == 0) {
    float s = 0.f;
    const float* wkr = wkL + (size_t)c * 512;
    const float* bqh = bq + (size_t)l * 512 + h * 128;
    for (int a = 0; a < 128; ++a) s = fmaf(wkr[a], bqh[a], s);
    bcat[(size_t)l * NF1_ + h * 128 + c] = s;
  }
}

// ---------------- embedding GEMM + fused BN partial stats ----------------
__global__ __launch_bounds__(256) void k_embed2(const float* __restrict__ x,
    const float* __restrict__ W, const float* __restrict__ b,
    float* __restrict__ out, float* __restrict__ ss, float* __restrict__ sq) {
  __shared__ float xs[128][16];
  __shared__ float wsm[16][128];
  __shared__ float sr[2][128], qr[2][128];
  const int blk = blockIdx.x;
  const int t = threadIdx.x;
  for (int i = t; i < 16 * 128; i += 256) wsm[i >> 7][i & 127] = W[i];
  for (int i = t; i < 128 * 16; i += 256) xs[i >> 4][i & 15] = x[(size_t)blk * 2048 + i];
  __syncthreads();
  const int c = t & 127, rg = t >> 7;
  float bc = b[c];
  float s = 0.f, q = 0.f;
  for (int r = rg * 64; r < rg * 64 + 64; ++r) {
    float v = bc;
#pragma unroll
    for (int f = 0; f < 16; ++f) v = fmaf(xs[r][f], wsm[f][c], v);
    out[(size_t)(blk * 128 + r) * 128 + c] = v;
    s += v; q += v * v;
  }
  sr[rg][c] = s; qr[rg][c] = q;
  __syncthreads();
  if (t < 128) { ss[blk * 128 + t] = sr[0][t] + sr[1][t]; sq[blk * 128 + t] = qr[0][t] + qr[1][t]; }
}

// ---------------- BatchNorm finalize / apply ----------------
template<int NC>
__global__ void k_bn_finalize(const float* __restrict__ sums, const float* __restrict__ sumsq,
                              const float* __restrict__ g, const float* __restrict__ be,
                              float* __restrict__ a, float* __restrict__ cc) {
  int c = blockIdx.x * 128 + threadIdx.x;
  if (c >= NC) return;
  float s = 0.f, q = 0.f;
  for (int b = 0; b < 128; ++b) { s += sums[b * NC + c]; q += sumsq[b * NC + c]; }
  float mean = s * (1.0f / N_);
  float var  = q * (1.0f / N_) - mean * mean;
  float inv  = rsqrtf(var + EPS_);
  float aa   = g[c] * inv;
  a[c]  = aa;
  cc[c] = be[c] - aa * mean;
}

template<int NC>
__global__ void k_bn_apply_gelu_cast(const float* __restrict__ xin, const float* __restrict__ a,
                                     const float* __restrict__ cc, bf16* __restrict__ outb) {
  int i4 = (blockIdx.x * 256 + threadIdx.x) * 4;
  int c = i4 & (NC - 1);
  float4 v = *reinterpret_cast<const float4*>(xin + i4);
  union { uint2 u2; bf16 h[4]; } pk;
  pk.h[0] = __float2bfloat16(gelu_f(fmaf(a[c + 0], v.x, cc[c + 0])));
  pk.h[1] = __float2bfloat16(gelu_f(fmaf(a[c + 1], v.y, cc[c + 1])));
  pk.h[2] = __float2bfloat16(gelu_f(fmaf(a[c + 2], v.z, cc[c + 2])));
  pk.h[3] = __float2bfloat16(gelu_f(fmaf(a[c + 3], v.w, cc[c + 3])));
  *reinterpret_cast<uint2*>(outb + i4) = pk.u2;
}

// ---------------- CSR build over dst ----------------
__global__ void k_count(const int* __restrict__ dst, int* __restrict__ deg) {
  int e = blockIdx.x * 256 + threadIdx.x;
  if (e < E_) atomicAdd(&deg[dst[e]], 1);
}

__global__ void k_bsum(const int* __restrict__ deg, int* __restrict__ bsum) {
  __shared__ int sh[256];
  int t = threadIdx.x;
  sh[t] = deg[blockIdx.x * 256 + t];
  __syncthreads();
  for (int d = 128; d > 0; d >>= 1) { if (t < d) sh[t] += sh[t + d]; __syncthreads(); }
  if (t == 0) bsum[blockIdx.x] = sh[0];
}

__global__ void k_boffs(const int* __restrict__ deg, const int* __restrict__ bsum,
                        int* __restrict__ offs) {
  __shared__ int sh[256];
  __shared__ int baseSh;
  int t = threadIdx.x;
  if (t < 64) {
    int v = bsum[t];
    int s = v;
    for (int d = 1; d < 64; d <<= 1) { int o = __shfl_up(s, d); if (t >= d) s += o; }
    if (t == (int)blockIdx.x) baseSh = s - v;
  }
  int v = deg[blockIdx.x * 256 + t];
  sh[t] = v;
  __syncthreads();
  for (int d = 1; d < 256; d <<= 1) {
    int add = (t >= d) ? sh[t - d] : 0;
    __syncthreads();
    sh[t] += add;
    __syncthreads();
  }
  offs[blockIdx.x * 256 + t] = baseSh + sh[t] - v;
  if (blockIdx.x == 63 && t == 255) offs[N_] = E_;
}

__global__ void k_scatter(const int* __restrict__ src, const int* __restrict__ dst,
                          const int* __restrict__ off, int* __restrict__ cursor,
                          int* __restrict__ srcs) {
  int e = blockIdx.x * 256 + threadIdx.x;
  if (e < E_) {
    int d = dst[e];
    int pos = off[d] + atomicAdd(&cursor[d], 1);
    srcs[pos] = src[e];
  }
}

// ---------------- bf16 MFMA GEMM ----------------
// MODE 2: fused routing: z fp32 (cols<512) / xr fp32 (cols 512..639).
// MODE 3: fp32 out + per-m-tile BN column partial stats.
// MODE 4: A fp32 pre-BN; staging applies BN(a,c)+GELU, casts bf16; fp32+bf16 out.
// MODE 5: fp32 out only, no bias.
template<int KDIM, int NOUT, int TM, int MODE>
__global__ __launch_bounds__(256) void k_mfma(
    const bf16* __restrict__ A, const float* __restrict__ Af,
    const bf16* __restrict__ BT, const float* __restrict__ bias,
    float* __restrict__ outF, bf16* __restrict__ outB,
    float* __restrict__ zfp, float* __restrict__ xrp,
    float* __restrict__ ss, float* __restrict__ sq,
    const float* __restrict__ aCol, const float* __restrict__ cCol) {
  constexpr int MF = TM / 32;
  __shared__ bf16 As[TM][72];
  __shared__ bf16 Bs[128][72];
  __shared__ float sred[2][128], qred[2][128];
  __shared__ float aS[MODE == 4 ? KDIM : 1], cS[MODE == 4 ? KDIM : 1];
  const int tid = threadIdx.x;
  const int wid = tid >> 6, lane = tid & 63;
  const int wr = wid >> 1, wc = wid & 1;
  const int m0 = blockIdx.x * TM, n0 = blockIdx.y * 128;
  const int ln = lane & 15, lq = lane >> 4;
  if constexpr (MODE == 4) {
    for (int i = tid; i < KDIM; i += 256) { aS[i] = aCol[i]; cS[i] = cCol[i]; }
    __syncthreads();
  }
  f32x4 acc[MF][4];
#pragma unroll
  for (int i = 0; i < MF; ++i)
#pragma unroll
    for (int j = 0; j < 4; ++j) acc[i][j] = (f32x4){0.f, 0.f, 0.f, 0.f};

  for (int k0 = 0; k0 < KDIM; k0 += 64) {
#pragma unroll
    for (int u = tid; u < TM * 8; u += 256) {
      int r = u >> 3, c = u & 7;
      if constexpr (MODE == 4) {
        const float4* ap = reinterpret_cast<const float4*>(Af + (size_t)(m0 + r) * KDIM + k0 + c * 8);
        float4 f0 = ap[0], f1 = ap[1];
        float f[8] = {f0.x, f0.y, f0.z, f0.w, f1.x, f1.y, f1.z, f1.w};
        int colb = k0 + c * 8;
        union { uint4 u4; bf16 h[8]; } pk;
#pragma unroll
        for (int j = 0; j < 8; ++j)
          pk.h[j] = __float2bfloat16(gelu_f(fmaf(aS[colb + j], f[j], cS[colb + j])));
        *(uint4*)(&As[r][c * 8]) = pk.u4;
      } else {
        *(uint4*)(&As[r][c * 8]) = *(const uint4*)(A + (size_t)(m0 + r) * KDIM + k0 + c * 8);
      }
    }
#pragma unroll
    for (int u = tid; u < 1024; u += 256) {
      int r = u >> 3, c = u & 7;
      *(uint4*)(&Bs[r][c * 8]) = *(const uint4*)(BT + (size_t)(n0 + r) * KDIM + k0 + c * 8);
    }
    __syncthreads();
#pragma unroll
    for (int kk = 0; kk < 2; ++kk) {
      bf16x8 af[MF], bg[4];
#pragma unroll
      for (int i = 0; i < MF; ++i)
        af[i] = *(const bf16x8*)(&As[wr * (TM / 2) + i * 16 + ln][kk * 32 + lq * 8]);
#pragma unroll
      for (int j = 0; j < 4; ++j)
        bg[j] = *(const bf16x8*)(&Bs[wc * 64 + j * 16 + ln][kk * 32 + lq * 8]);
#pragma unroll
      for (int i = 0; i < MF; ++i)
#pragma unroll
        for (int j = 0; j < 4; ++j)
          acc[i][j] = __builtin_amdgcn_mfma_f32_16x16x32_bf16(af[i], bg[j], acc[i][j], 0, 0, 0);
    }
    __syncthreads();
  }
  float ssj[4] = {0.f, 0.f, 0.f, 0.f}, sqj[4] = {0.f, 0.f, 0.f, 0.f};
#pragma unroll
  for (int i = 0; i < MF; ++i) {
#pragma unroll
    for (int j = 0; j < 4; ++j) {
      int gcol = n0 + wc * 64 + j * 16 + ln;
      float bv = 0.f;
      if constexpr (MODE != 5) bv = bias[gcol];
      int row0 = m0 + wr * (TM / 2) + i * 16 + lq * 4;
#pragma unroll
      for (int qq = 0; qq < 4; ++qq) {
        float val = acc[i][j][qq] + bv;
        int row = row0 + qq;
        if (MODE == 3) {
          outF[(size_t)row * NOUT + gcol] = val;
          ssj[j] += val; sqj[j] += val * val;
        } else if (MODE == 4) {
          outF[(size_t)row * NOUT + gcol] = val;
          outB[(size_t)row * NOUT + gcol] = __float2bfloat16(val);
        } else if (MODE == 5) {
          outF[(size_t)row * NOUT + gcol] = val;
        } else {
          if (n0 < 512) zfp[(size_t)row * 512 + gcol] = val;
          else          xrp[(size_t)row * H_ + (gcol - 512)] = val;
        }
      }
    }
  }
  if constexpr (MODE == 3) {
#pragma unroll
    for (int j = 0; j < 4; ++j) {
      ssj[j] += __shfl_xor(ssj[j], 16); ssj[j] += __shfl_xor(ssj[j], 32);
      sqj[j] += __shfl_xor(sqj[j], 16); sqj[j] += __shfl_xor(sqj[j], 32);
    }
    if (lq == 0) {
#pragma unroll
      for (int j = 0; j < 4; ++j) {
        sred[wr][wc * 64 + j * 16 + ln] = ssj[j];
        qred[wr][wc * 64 + j * 16 + ln] = sqj[j];
      }
    }
    __syncthreads();
    if (tid < 128) {
      ss[(size_t)blockIdx.x * NOUT + n0 + tid] = sred[0][tid] + sred[1][tid];
      sq[(size_t)blockIdx.x * NOUT + n0 + tid] = qred[0][tid] + qred[1][tid];
    }
  }
}

// ---------------- attention: gather hb only; aggregate hb into per-head agg ----------------
// logit_h = z[n, h*128+:] . hb[src,:];  agg~_h = sum pe*hb[src] / den_h  -> bf16 [N,512]
__global__ __launch_bounds__(256) void k_attn(const float* __restrict__ zf,
    const bf16* __restrict__ hb, const int* __restrict__ srcs,
    const int* __restrict__ off, bf16* __restrict__ aggB) {
  const int wave = threadIdx.x >> 6;
  const int lane = threadIdx.x & 63;
  const int bid = blockIdx.x;                      // 4096 blocks
  const int swz = ((bid & 7) << 9) | (bid >> 3);   // XCD-contiguous chunks
  const int node = swz * 4 + wave;
  const int sub = lane & 15;
  const float scale = 0.08838834764831845f;        // 1/sqrt(128)
  float qf[8];
  {
    const float4* qp = reinterpret_cast<const float4*>(zf + (size_t)node * 512) + lane * 2;
    float4 a = qp[0], b = qp[1];
    qf[0]=a.x; qf[1]=a.y; qf[2]=a.z; qf[3]=a.w;
    qf[4]=b.x; qf[5]=b.y; qf[6]=b.z; qf[7]=b.w;
  }
  float m = -1e30f, den = 0.f;
  float acc[8] = {0.f, 0.f, 0.f, 0.f, 0.f, 0.f, 0.f, 0.f};
  const int s0 = off[node], s1 = off[node + 1];
  if (s0 < s1) {
    int i0 = srcs[s0];
    int i1 = (s0 + 1 < s1) ? srcs[s0 + 1] : i0;
    uint4 h0 = *(const uint4*)(hb + (size_t)i0 * 128 + sub * 8);
    uint4 h1 = *(const uint4*)(hb + (size_t)i1 * 128 + sub * 8);
    for (int t = s0; t < s1; t += 2) {
      int j0 = (t + 2 < s1) ? srcs[t + 2] : i0;
      int j1 = (t + 3 < s1) ? srcs[t + 3] : i0;
      uint4 nh0 = *(const uint4*)(hb + (size_t)j0 * 128 + sub * 8);
      uint4 nh1 = *(const uint4*)(hb + (size_t)j1 * 128 + sub * 8);
      {
        float hf[8]; unpack8(h0, hf);
        float p = hf[0]*qf[0]+hf[1]*qf[1]+hf[2]*qf[2]+hf[3]*qf[3]
                + hf[4]*qf[4]+hf[5]*qf[5]+hf[6]*qf[6]+hf[7]*qf[7];
        p += __shfl_xor(p, 1); p += __shfl_xor(p, 2);
        p += __shfl_xor(p, 4); p += __shfl_xor(p, 8);
        float logit = p * scale;
        if (logit > m + 8.f) {
          float co = __expf(m - logit);
          den *= co;
#pragma unroll
          for (int j = 0; j < 8; ++j) acc[j] *= co;
          m = logit;
        }
        float pe = __expf(logit - m);
        den += pe;
#pragma unroll
        for (int j = 0; j < 8; ++j) acc[j] = fmaf(pe, hf[j], acc[j]);
      }
      if (t + 1 < s1) {
        float hf[8]; unpack8(h1, hf);
        float p = hf[0]*qf[0]+hf[1]*qf[1]+hf[2]*qf[2]+hf[3]*qf[3]
                + hf[4]*qf[4]+hf[5]*qf[5]+hf[6]*qf[6]+hf[7]*qf[7];
        p += __shfl_xor(p, 1); p += __shfl_xor(p, 2);
        p += __shfl_xor(p, 4); p += __shfl_xor(p, 8);
        float logit = p * scale;
        if (logit > m + 8.f) {
          float co = __expf(m - logit);
          den *= co;
#pragma unroll
          for (int j = 0; j < 8; ++j) acc[j] *= co;
          m = logit;
        }
        float pe = __expf(logit - m);
        den += pe;
#pragma unroll
        for (int j = 0; j < 8; ++j) acc[j] = fmaf(pe, hf[j], acc[j]);
      }
      h0 = nh0; h1 = nh1;
    }
  }
  float inv = 1.f / (den + 1e-16f);
  union { uint4 u4; bf16 h[8]; } pk;
#pragma unroll
  for (int j = 0; j < 8; ++j) pk.h[j] = __float2bfloat16(acc[j] * inv);
  *reinterpret_cast<uint4*>(aggB + (size_t)node * 512 + lane * 8) = pk.u4;
}

// ---------------- beta gate: out = out0 + bvm (if deg>0); gated = beta*xr + (1-beta)*out ----------------
__global__ __launch_bounds__(256) void k_beta(const float* __restrict__ out0,
    const float* __restrict__ xr, const float* __restrict__ Wb,
    const float* __restrict__ bvm, const int* __restrict__ off,
    bf16* __restrict__ gated) {
  const int wave = threadIdx.x >> 6;
  const int lane = threadIdx.x & 63;
  const int node = blockIdx.x * 4 + wave;
  const int c0 = lane * 2;
  bool hasE = off[node + 1] > off[node];
  float2 o = *reinterpret_cast<const float2*>(out0 + (size_t)node * H_ + c0);
  if (hasE) { o.x += bvm[c0]; o.y += bvm[c0 + 1]; }
  float2 xv = *reinterpret_cast<const float2*>(xr + (size_t)node * H_ + c0);
  float s = o.x * (Wb[c0] + Wb[256 + c0]) + xv.x * (Wb[128 + c0] - Wb[256 + c0])
          + o.y * (Wb[c0 + 1] + Wb[256 + c0 + 1]) + xv.y * (Wb[128 + c0 + 1] - Wb[256 + c0 + 1]);
#pragma unroll
  for (int d = 1; d < 64; d <<= 1) s += __shfl_xor(s, d);
  float beta = 1.f / (1.f + __expf(-s));
  union { unsigned u; bf16 h[2]; } pk;
  pk.h[0] = __float2bfloat16(beta * xv.x + (1.f - beta) * o.x);
  pk.h[1] = __float2bfloat16(beta * xv.y + (1.f - beta) * o.y);
  *reinterpret_cast<unsigned*>(gated + (size_t)node * H_ + c0) = pk.u;
}

// ---------------- fused segment max-pool + prediction (batch_index sorted) ----------------
__global__ __launch_bounds__(256) void k_poolpred(const float* __restrict__ h,
    const int* __restrict__ batch, const float* __restrict__ predW,
    const float* __restrict__ predb, float* __restrict__ out) {
  __shared__ float cm[2][128];
  __shared__ int range[2];
  const int g = blockIdx.x, t = threadIdx.x;
  if (t < 2) {
    int target = g + t;
    int lo = 0, hi = N_;
    while (lo < hi) { int mid = (lo + hi) >> 1; if (batch[mid] < target) lo = mid + 1; else hi = mid; }
    range[t] = lo;
  }
  __syncthreads();
  const int lo = range[0], hi = range[1];
  const int c = t & 127, rg = t >> 7;
  float m = -3.402823466e+38f;
  for (int r = lo + rg; r < hi; r += 2) m = fmaxf(m, h[(size_t)r * H_ + c]);
  cm[rg][c] = m;
  __syncthreads();
  if (t < 64) {
    float m0 = fmaxf(cm[0][t], cm[1][t]);
    float m1 = fmaxf(cm[0][t + 64], cm[1][t + 64]);
    float s = m0 * predW[t] + m1 * predW[t + 64];
#pragma unroll
    for (int d = 1; d < 64; d <<= 1) s += __shfl_xor(s, d);
    if (t == 0) out[g] = s + predb[0];
  }
}

extern "C" void kernel_launch(void* const* d_in, const int* in_sizes, int n_in,
                              void* d_out, int out_size, void* d_ws, size_t ws_size,
                              hipStream_t stream) {
  const float* x      = (const float*)d_in[0];
  const int*   edge   = (const int*)d_in[1];
  const int*   esrc   = edge;
  const int*   edst   = edge + E_;
  const int*   batch  = (const int*)d_in[2];
  const float* embW   = (const float*)d_in[3];
  const float* embb   = (const float*)d_in[4];
  const float* emb_g  = (const float*)d_in[5];
  const float* emb_be = (const float*)d_in[6];
  const float* Wq     = (const float*)d_in[7];
  const float* bq     = (const float*)d_in[8];
  const float* Wk     = (const float*)d_in[9];
  const float* Wv     = (const float*)d_in[11];
  const float* bv     = (const float*)d_in[12];
  const float* Wskip  = (const float*)d_in[13];
  const float* bskip  = (const float*)d_in[14];
  const float* Wbeta  = (const float*)d_in[15];
  const float* W1     = (const float*)d_in[16];
  const float* b1     = (const float*)d_in[17];
  const float* g1     = (const float*)d_in[18];
  const float* be1    = (const float*)d_in[19];
  const float* W2     = (const float*)d_in[20];
  const float* b2     = (const float*)d_in[21];
  const float* predW  = (const float*)d_in[22];
  const float* predb  = (const float*)d_in[23];

  // ---- workspace layout (aliased lifetimes) ----
  float* ws = (float*)d_ws;
  size_t o = 0;
  auto alloc_f = [&](size_t n) { float* p = ws + o; o += n; return p; };
  float* A32   = alloc_f((size_t)N_ * 512);   // zf (GEMM1->attn)  /  t1 (FFN1->FFN2)
  float* B32   = alloc_f((size_t)N_ * H_);    // out0 (Vproj->beta) / h32 (FFN2->pool)
  float* xr    = alloc_f((size_t)N_ * H_);
  float* stats = alloc_f(2 * 128 * DFF_);
  float* a_c   = alloc_f(DFF_);
  float* c_c   = alloc_f(DFF_);
  float* bcat  = alloc_f(5 * NF1_);
  float* bvm   = alloc_f(5 * 128);
  bf16* bp = (bf16*)(ws + o);
  size_t ob = 0;
  auto alloc_b = [&](size_t n) { bf16* p = bp + ob; ob += n; return p; };
  bf16* aggB = alloc_b((size_t)N_ * 512);
  bf16* hb   = alloc_b((size_t)N_ * H_);
  bf16* gated= alloc_b((size_t)N_ * H_);
  bf16* Wcat1= alloc_b((size_t)5 * WCAT1SZ);
  bf16* W1t  = alloc_b((size_t)5 * W1TSZ);
  bf16* W2t  = alloc_b((size_t)5 * W2TSZ);
  bf16* Wvs  = alloc_b((size_t)5 * WVSSZ);
  int* deg    = (int*)(bp + ob);
  int* offs   = deg + N_;
  int* cursor = offs + N_ + 1;
  int* srcs   = cursor + N_;
  int* bsum   = srcs + E_;       // 64

  float* zf   = A32;  float* t1 = A32;
  float* out0 = B32;  float* h32 = B32;

  // ---- weight prep ----
  k_ptrans<<<TRBLKS + 15, 256, 0, stream>>>(Wskip, W1, W2, bskip, bv,
                                            Wcat1, W1t, W2t, bcat, bvm);
  k_wvprep<<<320, 256, 0, stream>>>(Wv, Wvs);
  k_gmat<<<dim3(20, 2), 256, 0, stream>>>(Wq, Wk, bq, Wcat1, bcat);

  // ---- CSR build ----
  hipMemsetAsync(deg, 0, N_ * sizeof(int), stream);
  hipMemsetAsync(cursor, 0, N_ * sizeof(int), stream);
  k_count  <<<E_ / 256, 256, 0, stream>>>(edst, deg);
  k_bsum   <<<64, 256, 0, stream>>>(deg, bsum);
  k_boffs  <<<64, 256, 0, stream>>>(deg, bsum, offs);
  k_scatter<<<E_ / 256, 256, 0, stream>>>(esrc, edst, offs, cursor, srcs);

  // ---- embedding (+fused stats) + BN + GELU -> bf16 ----
  k_embed2<<<128, 256, 0, stream>>>(x, embW, embb, A32, stats, stats + 128 * 128);
  k_bn_finalize<128><<<1, 128, 0, stream>>>(stats, stats + 128 * 128, emb_g, emb_be, a_c, c_c);
  k_bn_apply_gelu_cast<128><<<N_ * H_ / 1024, 256, 0, stream>>>(A32, a_c, c_c, hb);

  for (int l = 0; l < L_; ++l) {
    const float* Wb_ = Wbeta + (size_t)l * 3 * H_;
    const float* b1_ = b1 + (size_t)l * DFF_;
    const float* g1_ = g1 + (size_t)l * DFF_;
    const float* be1_= be1 + (size_t)l * DFF_;
    const float* b2_ = b2 + (size_t)l * H_;

    // GEMM1: z | xr  (NOUT = 640)
    k_mfma<128, NF1_, 128, 2><<<dim3(N_ / 128, NF1_ / 128), 256, 0, stream>>>(
        hb, nullptr, Wcat1 + (size_t)l * WCAT1SZ, bcat + (size_t)l * NF1_,
        nullptr, nullptr, zf, xr, nullptr, nullptr, nullptr, nullptr);

    k_attn<<<N_ / 4, 256, 0, stream>>>(zf, hb, srcs, offs, aggB);

    // V projection: out0 = aggB @ Wvs (no bias)
    k_mfma<512, 128, 64, 5><<<dim3(N_ / 64, 1), 256, 0, stream>>>(
        aggB, nullptr, Wvs + (size_t)l * WVSSZ, nullptr,
        out0, nullptr, nullptr, nullptr, nullptr, nullptr, nullptr, nullptr);

    k_beta<<<N_ / 4, 256, 0, stream>>>(out0, xr, Wb_, bvm + (size_t)l * 128, offs, gated);

    // FFN1: fp32 out + fused BN partial stats
    k_mfma<128, 512, 128, 3><<<dim3(N_ / 128, 4), 256, 0, stream>>>(
        gated, nullptr, W1t + (size_t)l * W1TSZ, b1_, t1, nullptr, nullptr, nullptr,
        stats, stats + 128 * 512, nullptr, nullptr);

    k_bn_finalize<512><<<4, 128, 0, stream>>>(stats, stats + 128 * 512, g1_, be1_, a_c, c_c);

    // FFN2: BN+GELU fused into fp32 A-staging
    k_mfma<512, 128, 64, 4><<<dim3(N_ / 64, 1), 256, 0, stream>>>(
        nullptr, t1, W2t + (size_t)l * W2TSZ, b2_, h32, hb, nullptr, nullptr,
        nullptr, nullptr, a_c, c_c);
  }

  // ---- fused pooling + prediction ----
  k_poolpred<<<G_, 256, 0, stream>>>(h32, batch, predW, predb, (float*)d_out);
}

// Round 12
// 696.732 us; speedup vs baseline: 1.3780x; 1.0992x over previous
//
#include <hip/hip_runtime.h>
#include <hip/hip_bf16.h>

using bf16 = __hip_bfloat16;
typedef __attribute__((ext_vector_type(8))) short bf16x8;
typedef __attribute__((ext_vector_type(4))) float f32x4;

constexpr int N_   = 16384;
constexpr int E_   = 262144;
constexpr int F_   = 16;
constexpr int H_   = 128;
constexpr int NF1_ = 640;    // z(512) | skip(128)
constexpr int DFF_ = 512;
constexpr int G_   = 128;
constexpr int L_   = 5;
constexpr float EPS_ = 1e-5f;

constexpr int WCAT1SZ = NF1_ * 128;    // 81920
constexpr int W1TSZ   = 512 * 128;
constexpr int W2TSZ   = 512 * 128;
constexpr int WVSSZ   = 128 * 512;     // Wvs: [128 n][512 k]
constexpr int TRBLKS  = 5 * 144;       // Ws:16 + W1:64 + W2:64 per layer

__device__ __forceinline__ float gelu_f(float x) {
  return 0.5f * x * (1.0f + erff(x * 0.70710678118654752440f));
}

__device__ __forceinline__ void unpack8(const uint4 w, float* f) {
  f[0] = __uint_as_float(w.x << 16); f[1] = __uint_as_float(w.x & 0xFFFF0000u);
  f[2] = __uint_as_float(w.y << 16); f[3] = __uint_as_float(w.y & 0xFFFF0000u);
  f[4] = __uint_as_float(w.z << 16); f[5] = __uint_as_float(w.z & 0xFFFF0000u);
  f[6] = __uint_as_float(w.w << 16); f[7] = __uint_as_float(w.w & 0xFFFF0000u);
}

// ---------------- weight prep: transposes (Ws,W1,W2) + bias tails ----------------
__global__ __launch_bounds__(256) void k_ptrans(
    const float* __restrict__ Ws, const float* __restrict__ W1,
    const float* __restrict__ W2, const float* __restrict__ bs,
    const float* __restrict__ bv,
    bf16* __restrict__ Wcat1, bf16* __restrict__ W1t, bf16* __restrict__ W2t,
    float* __restrict__ bcat, float* __restrict__ bvm) {
  __shared__ float lds[32][33];
  const int b = blockIdx.x;
  if (b >= TRBLKS) {                 // tails: bcat skip-cols + bvm
    int j = (b - TRBLKS) * 256 + threadIdx.x;
    if (j < 5 * NF1_) {
      int l = j / NF1_, c = j % NF1_;
      if (c >= 512) bcat[j] = bs[l * 128 + (c - 512)];
    } else if (j < 5 * NF1_ + 5 * 128) {
      int j2 = j - 5 * NF1_;
      int l = j2 / 128, n = j2 % 128;
      bvm[j2] = 0.25f * (bv[l * 512 + n] + bv[l * 512 + 128 + n]
                       + bv[l * 512 + 256 + n] + bv[l * 512 + 384 + n]);
    }
    return;
  }
  const int l = b / 144, t = b % 144;
  const float* src; int C; bf16* dst; int dld; int nof; int tt;
  if (t < 16) {         // Ws: [128][128] -> Wcat1 rows 512..639
    tt = t;
    src = Ws + (size_t)l * 128 * 128; C = 128;
    dst = Wcat1 + (size_t)l * WCAT1SZ; dld = 128; nof = 512;
  } else if (t < 80) {  // W1
    tt = t - 16;
    src = W1 + (size_t)l * 128 * 512; C = 512;
    dst = W1t + (size_t)l * W1TSZ; dld = 128; nof = 0;
  } else {              // W2
    tt = t - 80;
    src = W2 + (size_t)l * 512 * 128; C = 128;
    dst = W2t + (size_t)l * W2TSZ; dld = 512; nof = 0;
  }
  const int tpr = C >> 5;
  const int r0 = (tt / tpr) * 32, c0 = (tt % tpr) * 32;
  const int j = threadIdx.x & 31, g = threadIdx.x >> 5;
#pragma unroll
  for (int ii = 0; ii < 4; ++ii) {
    int i = g * 4 + ii;
    lds[i][j] = src[(size_t)(r0 + i) * C + c0 + j];
  }
  __syncthreads();
#pragma unroll
  for (int ii = 0; ii < 4; ++ii) {
    int i = g * 4 + ii;
    dst[(size_t)(nof + c0 + i) * dld + r0 + j] = __float2bfloat16(lds[j][i]);
  }
}

// ---------------- Wvs: per head, Wvs[n][h*128+c] = 0.25 * Wv[c][h*128+n] ----------------
__global__ __launch_bounds__(256) void k_wvprep(const float* __restrict__ Wv,
                                                bf16* __restrict__ Wvs) {
  __shared__ float lds[32][33];
  const int b = blockIdx.x;            // 5*4*16
  const int l = b / 64, rest = b % 64;
  const int h = rest / 16, tt = rest % 16;
  const int r0 = (tt / 4) * 32, c0 = (tt % 4) * 32;
  const float* src = Wv + (size_t)l * 128 * 512 + h * 128;
  bf16* dst = Wvs + (size_t)l * WVSSZ;
  const int j = threadIdx.x & 31, g = threadIdx.x >> 5;
#pragma unroll
  for (int ii = 0; ii < 4; ++ii) {
    int i = g * 4 + ii;
    lds[i][j] = src[(size_t)(r0 + i) * 512 + c0 + j];
  }
  __syncthreads();
#pragma unroll
  for (int ii = 0; ii < 4; ++ii) {
    int i = g * 4 + ii;
    dst[(size_t)(c0 + i) * 512 + h * 128 + r0 + j] = __float2bfloat16(0.25f * lds[j][i]);
  }
}

// ---------------- G = Wq_h @ Wk_h^T per (layer, head); writes GT rows + z-bias ----------------
__global__ __launch_bounds__(256) void k_gmat(
    const float* __restrict__ Wq, const float* __restrict__ Wk,
    const float* __restrict__ bq,
    bf16* __restrict__ Wcat1, float* __restrict__ bcat) {
  __shared__ float lq[32][132];
  __shared__ float lk[32][132];
  const int l = blockIdx.x >> 2, h = blockIdx.x & 3;
  const int half = blockIdx.y;
  const int tid = threadIdx.x;
  const int c = tid & 127, ch = tid >> 7;
  const int cp0 = half * 64 + ch * 32;
  const float* wqL = Wq + (size_t)l * 128 * 512 + h * 128;
  const float* wkL = Wk + (size_t)l * 128 * 512 + h * 128;
  float acc[32];
#pragma unroll
  for (int j = 0; j < 32; ++j) acc[j] = 0.f;
  for (int a0 = 0; a0 < 128; a0 += 32) {
    __syncthreads();
#pragma unroll
    for (int q4 = 0; q4 < 4; ++q4) {
      int f4 = tid * 4 + q4;
      int row = f4 >> 3, af = f4 & 7;
      float4 gq = *reinterpret_cast<const float4*>(wqL + (size_t)row * 512 + a0 + af * 4);
      float4 gk = *reinterpret_cast<const float4*>(wkL + (size_t)row * 512 + a0 + af * 4);
      lq[af * 4 + 0][row] = gq.x; lq[af * 4 + 1][row] = gq.y;
      lq[af * 4 + 2][row] = gq.z; lq[af * 4 + 3][row] = gq.w;
      lk[af * 4 + 0][row] = gk.x; lk[af * 4 + 1][row] = gk.y;
      lk[af * 4 + 2][row] = gk.z; lk[af * 4 + 3][row] = gk.w;
    }
    __syncthreads();
    for (int a = 0; a < 32; ++a) {
      float wq = lq[a][c];
#pragma unroll
      for (int j = 0; j < 32; ++j) acc[j] = fmaf(wq, lk[a][cp0 + j], acc[j]);
    }
  }
  bf16* gt = Wcat1 + (size_t)l * WCAT1SZ;
#pragma unroll
  for (int j = 0; j < 32; ++j)
    gt[(size_t)(h * 128 + cp0 + j) * 128 + c] = __float2bfloat16(acc[j]);
  if (half == 0 && ch == 0) {
    float s = 0.f;
    const float* wkr = wkL + (size_t)c * 512;
    const float* bqh = bq + (size_t)l * 512 + h * 128;
    for (int a = 0; a < 128; ++a) s = fmaf(wkr[a], bqh[a], s);
    bcat[(size_t)l * NF1_ + h * 128 + c] = s;
  }
}

// ---------------- embedding GEMM + fused BN partial stats ----------------
__global__ __launch_bounds__(256) void k_embed2(const float* __restrict__ x,
    const float* __restrict__ W, const float* __restrict__ b,
    float* __restrict__ out, float* __restrict__ ss, float* __restrict__ sq) {
  __shared__ float xs[128][16];
  __shared__ float wsm[16][128];
  __shared__ float sr[2][128], qr[2][128];
  const int blk = blockIdx.x;
  const int t = threadIdx.x;
  for (int i = t; i < 16 * 128; i += 256) wsm[i >> 7][i & 127] = W[i];
  for (int i = t; i < 128 * 16; i += 256) xs[i >> 4][i & 15] = x[(size_t)blk * 2048 + i];
  __syncthreads();
  const int c = t & 127, rg = t >> 7;
  float bc = b[c];
  float s = 0.f, q = 0.f;
  for (int r = rg * 64; r < rg * 64 + 64; ++r) {
    float v = bc;
#pragma unroll
    for (int f = 0; f < 16; ++f) v = fmaf(xs[r][f], wsm[f][c], v);
    out[(size_t)(blk * 128 + r) * 128 + c] = v;
    s += v; q += v * v;
  }
  sr[rg][c] = s; qr[rg][c] = q;
  __syncthreads();
  if (t < 128) { ss[blk * 128 + t] = sr[0][t] + sr[1][t]; sq[blk * 128 + t] = qr[0][t] + qr[1][t]; }
}

// ---------------- BatchNorm finalize / apply ----------------
template<int NC>
__global__ void k_bn_finalize(const float* __restrict__ sums, const float* __restrict__ sumsq,
                              const float* __restrict__ g, const float* __restrict__ be,
                              float* __restrict__ a, float* __restrict__ cc) {
  int c = blockIdx.x * 128 + threadIdx.x;
  if (c >= NC) return;
  float s = 0.f, q = 0.f;
  for (int b = 0; b < 128; ++b) { s += sums[b * NC + c]; q += sumsq[b * NC + c]; }
  float mean = s * (1.0f / N_);
  float var  = q * (1.0f / N_) - mean * mean;
  float inv  = rsqrtf(var + EPS_);
  float aa   = g[c] * inv;
  a[c]  = aa;
  cc[c] = be[c] - aa * mean;
}

template<int NC>
__global__ void k_bn_apply_gelu_cast(const float* __restrict__ xin, const float* __restrict__ a,
                                     const float* __restrict__ cc, bf16* __restrict__ outb) {
  int i4 = (blockIdx.x * 256 + threadIdx.x) * 4;
  int c = i4 & (NC - 1);
  float4 v = *reinterpret_cast<const float4*>(xin + i4);
  union { uint2 u2; bf16 h[4]; } pk;
  pk.h[0] = __float2bfloat16(gelu_f(fmaf(a[c + 0], v.x, cc[c + 0])));
  pk.h[1] = __float2bfloat16(gelu_f(fmaf(a[c + 1], v.y, cc[c + 1])));
  pk.h[2] = __float2bfloat16(gelu_f(fmaf(a[c + 2], v.z, cc[c + 2])));
  pk.h[3] = __float2bfloat16(gelu_f(fmaf(a[c + 3], v.w, cc[c + 3])));
  *reinterpret_cast<uint2*>(outb + i4) = pk.u2;
}

// ---------------- CSR build over dst ----------------
__global__ void k_count(const int* __restrict__ dst, int* __restrict__ deg) {
  int e = blockIdx.x * 256 + threadIdx.x;
  if (e < E_) atomicAdd(&deg[dst[e]], 1);
}

__global__ void k_bsum(const int* __restrict__ deg, int* __restrict__ bsum) {
  __shared__ int sh[256];
  int t = threadIdx.x;
  sh[t] = deg[blockIdx.x * 256 + t];
  __syncthreads();
  for (int d = 128; d > 0; d >>= 1) { if (t < d) sh[t] += sh[t + d]; __syncthreads(); }
  if (t == 0) bsum[blockIdx.x] = sh[0];
}

__global__ void k_boffs(const int* __restrict__ deg, const int* __restrict__ bsum,
                        int* __restrict__ offs) {
  __shared__ int sh[256];
  __shared__ int baseSh;
  int t = threadIdx.x;
  if (t < 64) {
    int v = bsum[t];
    int s = v;
    for (int d = 1; d < 64; d <<= 1) { int o = __shfl_up(s, d); if (t >= d) s += o; }
    if (t == (int)blockIdx.x) baseSh = s - v;
  }
  int v = deg[blockIdx.x * 256 + t];
  sh[t] = v;
  __syncthreads();
  for (int d = 1; d < 256; d <<= 1) {
    int add = (t >= d) ? sh[t - d] : 0;
    __syncthreads();
    sh[t] += add;
    __syncthreads();
  }
  offs[blockIdx.x * 256 + t] = baseSh + sh[t] - v;
  if (blockIdx.x == 63 && t == 255) offs[N_] = E_;
}

__global__ void k_scatter(const int* __restrict__ src, const int* __restrict__ dst,
                          const int* __restrict__ off, int* __restrict__ cursor,
                          int* __restrict__ srcs) {
  int e = blockIdx.x * 256 + threadIdx.x;
  if (e < E_) {
    int d = dst[e];
    int pos = off[d] + atomicAdd(&cursor[d], 1);
    srcs[pos] = src[e];
  }
}

// ---------------- bf16 MFMA GEMM ----------------
// KLD = row stride of A/BT (K dim of the full matrix); KDIM = K extent this block loops.
// MODE 2: fused routing: z fp32 (cols<512) / xr fp32 (cols 512..639). grid-y = n-tile.
// MODE 3: fp32 out + per-m-tile BN column partial stats. grid-y = n-tile.
// MODE 4: split-K FFN2: A fp32 pre-BN; staging applies BN(a,c)+GELU, casts bf16;
//         partial fp32 out (no bias). grid-y = ks.
// MODE 5: split-K Vproj: bf16 A; partial fp32 out (no bias). grid-y = ks.
template<int KDIM, int KLD, int NOUT, int TM, int MODE>
__global__ __launch_bounds__(256) void k_mfma(
    const bf16* __restrict__ A, const float* __restrict__ Af,
    const bf16* __restrict__ BT, const float* __restrict__ bias,
    float* __restrict__ outF, bf16* __restrict__ outB,
    float* __restrict__ zfp, float* __restrict__ xrp,
    float* __restrict__ ss, float* __restrict__ sq,
    const float* __restrict__ aCol, const float* __restrict__ cCol) {
  constexpr int MF = TM / 32;
  constexpr bool SPLITK = (MODE == 4 || MODE == 5);
  __shared__ bf16 As[TM][72];
  __shared__ bf16 Bs[128][72];
  __shared__ float sred[2][128], qred[2][128];
  __shared__ float aS[MODE == 4 ? KDIM : 1], cS[MODE == 4 ? KDIM : 1];
  const int tid = threadIdx.x;
  const int wid = tid >> 6, lane = tid & 63;
  const int wr = wid >> 1, wc = wid & 1;
  const int m0 = blockIdx.x * TM;
  const int n0 = SPLITK ? 0 : blockIdx.y * 128;
  const int ks = SPLITK ? blockIdx.y : 0;
  const int ln = lane & 15, lq = lane >> 4;
  const size_t koff = (size_t)ks * KDIM;
  if constexpr (MODE == 4) {
    for (int i = tid; i < KDIM; i += 256) { aS[i] = aCol[koff + i]; cS[i] = cCol[koff + i]; }
    __syncthreads();
  }
  f32x4 acc[MF][4];
#pragma unroll
  for (int i = 0; i < MF; ++i)
#pragma unroll
    for (int j = 0; j < 4; ++j) acc[i][j] = (f32x4){0.f, 0.f, 0.f, 0.f};

  for (int k0 = 0; k0 < KDIM; k0 += 64) {
#pragma unroll
    for (int u = tid; u < TM * 8; u += 256) {
      int r = u >> 3, c = u & 7;
      if constexpr (MODE == 4) {
        const float4* ap = reinterpret_cast<const float4*>(Af + (size_t)(m0 + r) * KLD + koff + k0 + c * 8);
        float4 f0 = ap[0], f1 = ap[1];
        float f[8] = {f0.x, f0.y, f0.z, f0.w, f1.x, f1.y, f1.z, f1.w};
        int colb = k0 + c * 8;
        union { uint4 u4; bf16 h[8]; } pk;
#pragma unroll
        for (int j = 0; j < 8; ++j)
          pk.h[j] = __float2bfloat16(gelu_f(fmaf(aS[colb + j], f[j], cS[colb + j])));
        *(uint4*)(&As[r][c * 8]) = pk.u4;
      } else {
        *(uint4*)(&As[r][c * 8]) = *(const uint4*)(A + (size_t)(m0 + r) * KLD + koff + k0 + c * 8);
      }
    }
#pragma unroll
    for (int u = tid; u < 1024; u += 256) {
      int r = u >> 3, c = u & 7;
      *(uint4*)(&Bs[r][c * 8]) = *(const uint4*)(BT + (size_t)(n0 + r) * KLD + koff + k0 + c * 8);
    }
    __syncthreads();
#pragma unroll
    for (int kk = 0; kk < 2; ++kk) {
      bf16x8 af[MF], bg[4];
#pragma unroll
      for (int i = 0; i < MF; ++i)
        af[i] = *(const bf16x8*)(&As[wr * (TM / 2) + i * 16 + ln][kk * 32 + lq * 8]);
#pragma unroll
      for (int j = 0; j < 4; ++j)
        bg[j] = *(const bf16x8*)(&Bs[wc * 64 + j * 16 + ln][kk * 32 + lq * 8]);
#pragma unroll
      for (int i = 0; i < MF; ++i)
#pragma unroll
        for (int j = 0; j < 4; ++j)
          acc[i][j] = __builtin_amdgcn_mfma_f32_16x16x32_bf16(af[i], bg[j], acc[i][j], 0, 0, 0);
    }
    __syncthreads();
  }
  float* outP = SPLITK ? (outF + (size_t)ks * N_ * NOUT) : outF;
  float ssj[4] = {0.f, 0.f, 0.f, 0.f}, sqj[4] = {0.f, 0.f, 0.f, 0.f};
#pragma unroll
  for (int i = 0; i < MF; ++i) {
#pragma unroll
    for (int j = 0; j < 4; ++j) {
      int gcol = n0 + wc * 64 + j * 16 + ln;
      float bv = 0.f;
      if constexpr (MODE == 2 || MODE == 3) bv = bias[gcol];
      int row0 = m0 + wr * (TM / 2) + i * 16 + lq * 4;
#pragma unroll
      for (int qq = 0; qq < 4; ++qq) {
        float val = acc[i][j][qq] + bv;
        int row = row0 + qq;
        if (MODE == 3) {
          outP[(size_t)row * NOUT + gcol] = val;
          ssj[j] += val; sqj[j] += val * val;
        } else if (MODE == 4 || MODE == 5) {
          outP[(size_t)row * NOUT + gcol] = val;
        } else {
          if (n0 < 512) zfp[(size_t)row * 512 + gcol] = val;
          else          xrp[(size_t)row * H_ + (gcol - 512)] = val;
        }
      }
    }
  }
  if constexpr (MODE == 3) {
#pragma unroll
    for (int j = 0; j < 4; ++j) {
      ssj[j] += __shfl_xor(ssj[j], 16); ssj[j] += __shfl_xor(ssj[j], 32);
      sqj[j] += __shfl_xor(sqj[j], 16); sqj[j] += __shfl_xor(sqj[j], 32);
    }
    if (lq == 0) {
#pragma unroll
      for (int j = 0; j < 4; ++j) {
        sred[wr][wc * 64 + j * 16 + ln] = ssj[j];
        qred[wr][wc * 64 + j * 16 + ln] = sqj[j];
      }
    }
    __syncthreads();
    if (tid < 128) {
      ss[(size_t)blockIdx.x * NOUT + n0 + tid] = sred[0][tid] + sred[1][tid];
      sq[(size_t)blockIdx.x * NOUT + n0 + tid] = qred[0][tid] + qred[1][tid];
    }
  }
}

// ---------------- attention: gather hb only; aggregate hb into per-head agg ----------------
__global__ __launch_bounds__(256) void k_attn(const float* __restrict__ zf,
    const bf16* __restrict__ hb, const int* __restrict__ srcs,
    const int* __restrict__ off, bf16* __restrict__ aggB) {
  const int wave = threadIdx.x >> 6;
  const int lane = threadIdx.x & 63;
  const int bid = blockIdx.x;                      // 4096 blocks
  const int swz = ((bid & 7) << 9) | (bid >> 3);   // XCD-contiguous chunks
  const int node = swz * 4 + wave;
  const int sub = lane & 15;
  const float scale = 0.08838834764831845f;        // 1/sqrt(128)
  float qf[8];
  {
    const float4* qp = reinterpret_cast<const float4*>(zf + (size_t)node * 512) + lane * 2;
    float4 a = qp[0], b = qp[1];
    qf[0]=a.x; qf[1]=a.y; qf[2]=a.z; qf[3]=a.w;
    qf[4]=b.x; qf[5]=b.y; qf[6]=b.z; qf[7]=b.w;
  }
  float m = -1e30f, den = 0.f;
  float acc[8] = {0.f, 0.f, 0.f, 0.f, 0.f, 0.f, 0.f, 0.f};
  const int s0 = off[node], s1 = off[node + 1];
  if (s0 < s1) {
    int i0 = srcs[s0];
    int i1 = (s0 + 1 < s1) ? srcs[s0 + 1] : i0;
    uint4 h0 = *(const uint4*)(hb + (size_t)i0 * 128 + sub * 8);
    uint4 h1 = *(const uint4*)(hb + (size_t)i1 * 128 + sub * 8);
    for (int t = s0; t < s1; t += 2) {
      int j0 = (t + 2 < s1) ? srcs[t + 2] : i0;
      int j1 = (t + 3 < s1) ? srcs[t + 3] : i0;
      uint4 nh0 = *(const uint4*)(hb + (size_t)j0 * 128 + sub * 8);
      uint4 nh1 = *(const uint4*)(hb + (size_t)j1 * 128 + sub * 8);
      {
        float hf[8]; unpack8(h0, hf);
        float p = hf[0]*qf[0]+hf[1]*qf[1]+hf[2]*qf[2]+hf[3]*qf[3]
                + hf[4]*qf[4]+hf[5]*qf[5]+hf[6]*qf[6]+hf[7]*qf[7];
        p += __shfl_xor(p, 1); p += __shfl_xor(p, 2);
        p += __shfl_xor(p, 4); p += __shfl_xor(p, 8);
        float logit = p * scale;
        if (logit > m + 8.f) {
          float co = __expf(m - logit);
          den *= co;
#pragma unroll
          for (int j = 0; j < 8; ++j) acc[j] *= co;
          m = logit;
        }
        float pe = __expf(logit - m);
        den += pe;
#pragma unroll
        for (int j = 0; j < 8; ++j) acc[j] = fmaf(pe, hf[j], acc[j]);
      }
      if (t + 1 < s1) {
        float hf[8]; unpack8(h1, hf);
        float p = hf[0]*qf[0]+hf[1]*qf[1]+hf[2]*qf[2]+hf[3]*qf[3]
                + hf[4]*qf[4]+hf[5]*qf[5]+hf[6]*qf[6]+hf[7]*qf[7];
        p += __shfl_xor(p, 1); p += __shfl_xor(p, 2);
        p += __shfl_xor(p, 4); p += __shfl_xor(p, 8);
        float logit = p * scale;
        if (logit > m + 8.f) {
          float co = __expf(m - logit);
          den *= co;
#pragma unroll
          for (int j = 0; j < 8; ++j) acc[j] *= co;
          m = logit;
        }
        float pe = __expf(logit - m);
        den += pe;
#pragma unroll
        for (int j = 0; j < 8; ++j) acc[j] = fmaf(pe, hf[j], acc[j]);
      }
      h0 = nh0; h1 = nh1;
    }
  }
  float inv = 1.f / (den + 1e-16f);
  union { uint4 u4; bf16 h[8]; } pk;
#pragma unroll
  for (int j = 0; j < 8; ++j) pk.h[j] = __float2bfloat16(acc[j] * inv);
  *reinterpret_cast<uint4*>(aggB + (size_t)node * 512 + lane * 8) = pk.u4;
}

// ---------------- Vproj reduce + beta gate: out = Σ4 partials (+bvm if deg>0) ----------------
__global__ __launch_bounds__(256) void k_vredbeta(const float* __restrict__ vp,
    const float* __restrict__ xr, const float* __restrict__ Wb,
    const float* __restrict__ bvm, const int* __restrict__ off,
    bf16* __restrict__ gated) {
  const int wave = threadIdx.x >> 6;
  const int lane = threadIdx.x & 63;
  const int node = blockIdx.x * 4 + wave;
  const int c0 = lane * 2;
  bool hasE = off[node + 1] > off[node];
  const size_t base = (size_t)node * H_ + c0;
  const size_t stride = (size_t)N_ * H_;
  float2 p0 = *reinterpret_cast<const float2*>(vp + base);
  float2 p1 = *reinterpret_cast<const float2*>(vp + stride + base);
  float2 p2 = *reinterpret_cast<const float2*>(vp + 2 * stride + base);
  float2 p3 = *reinterpret_cast<const float2*>(vp + 3 * stride + base);
  float2 o;
  o.x = ((p0.x + p1.x) + p2.x) + p3.x;
  o.y = ((p0.y + p1.y) + p2.y) + p3.y;
  if (hasE) { o.x += bvm[c0]; o.y += bvm[c0 + 1]; }
  float2 xv = *reinterpret_cast<const float2*>(xr + base);
  float s = o.x * (Wb[c0] + Wb[256 + c0]) + xv.x * (Wb[128 + c0] - Wb[256 + c0])
          + o.y * (Wb[c0 + 1] + Wb[256 + c0 + 1]) + xv.y * (Wb[128 + c0 + 1] - Wb[256 + c0 + 1]);
#pragma unroll
  for (int d = 1; d < 64; d <<= 1) s += __shfl_xor(s, d);
  float beta = 1.f / (1.f + __expf(-s));
  union { unsigned u; bf16 h[2]; } pk;
  pk.h[0] = __float2bfloat16(beta * xv.x + (1.f - beta) * o.x);
  pk.h[1] = __float2bfloat16(beta * xv.y + (1.f - beta) * o.y);
  *reinterpret_cast<unsigned*>(gated + base) = pk.u;
}

// ---------------- FFN2 reduce: h32 = Σ4 partials + b2; hb = bf16 ----------------
__global__ __launch_bounds__(256) void k_f2red(const float* __restrict__ fp,
    const float* __restrict__ b2, float* __restrict__ h32, bf16* __restrict__ hb) {
  const int i4 = (blockIdx.x * 256 + threadIdx.x) * 4;
  const int c = i4 & 127;
  const size_t stride = (size_t)N_ * H_;
  float4 a0 = *reinterpret_cast<const float4*>(fp + i4);
  float4 a1 = *reinterpret_cast<const float4*>(fp + stride + i4);
  float4 a2 = *reinterpret_cast<const float4*>(fp + 2 * stride + i4);
  float4 a3 = *reinterpret_cast<const float4*>(fp + 3 * stride + i4);
  float4 s;
  s.x = ((a0.x + a1.x) + a2.x) + a3.x + b2[c + 0];
  s.y = ((a0.y + a1.y) + a2.y) + a3.y + b2[c + 1];
  s.z = ((a0.z + a1.z) + a2.z) + a3.z + b2[c + 2];
  s.w = ((a0.w + a1.w) + a2.w) + a3.w + b2[c + 3];
  *reinterpret_cast<float4*>(h32 + i4) = s;
  union { uint2 u2; bf16 h[4]; } pk;
  pk.h[0] = __float2bfloat16(s.x); pk.h[1] = __float2bfloat16(s.y);
  pk.h[2] = __float2bfloat16(s.z); pk.h[3] = __float2bfloat16(s.w);
  *reinterpret_cast<uint2*>(hb + i4) = pk.u2;
}

// ---------------- fused segment max-pool + prediction (batch_index sorted) ----------------
__global__ __launch_bounds__(256) void k_poolpred(const float* __restrict__ h,
    const int* __restrict__ batch, const float* __restrict__ predW,
    const float* __restrict__ predb, float* __restrict__ out) {
  __shared__ float cm[2][128];
  __shared__ int range[2];
  const int g = blockIdx.x, t = threadIdx.x;
  if (t < 2) {
    int target = g + t;
    int lo = 0, hi = N_;
    while (lo < hi) { int mid = (lo + hi) >> 1; if (batch[mid] < target) lo = mid + 1; else hi = mid; }
    range[t] = lo;
  }
  __syncthreads();
  const int lo = range[0], hi = range[1];
  const int c = t & 127, rg = t >> 7;
  float m = -3.402823466e+38f;
  for (int r = lo + rg; r < hi; r += 2) m = fmaxf(m, h[(size_t)r * H_ + c]);
  cm[rg][c] = m;
  __syncthreads();
  if (t < 64) {
    float m0 = fmaxf(cm[0][t], cm[1][t]);
    float m1 = fmaxf(cm[0][t + 64], cm[1][t + 64]);
    float s = m0 * predW[t] + m1 * predW[t + 64];
#pragma unroll
    for (int d = 1; d < 64; d <<= 1) s += __shfl_xor(s, d);
    if (t == 0) out[g] = s + predb[0];
  }
}

extern "C" void kernel_launch(void* const* d_in, const int* in_sizes, int n_in,
                              void* d_out, int out_size, void* d_ws, size_t ws_size,
                              hipStream_t stream) {
  const float* x      = (const float*)d_in[0];
  const int*   edge   = (const int*)d_in[1];
  const int*   esrc   = edge;
  const int*   edst   = edge + E_;
  const int*   batch  = (const int*)d_in[2];
  const float* embW   = (const float*)d_in[3];
  const float* embb   = (const float*)d_in[4];
  const float* emb_g  = (const float*)d_in[5];
  const float* emb_be = (const float*)d_in[6];
  const float* Wq     = (const float*)d_in[7];
  const float* bq     = (const float*)d_in[8];
  const float* Wk     = (const float*)d_in[9];
  const float* Wv     = (const float*)d_in[11];
  const float* bv     = (const float*)d_in[12];
  const float* Wskip  = (const float*)d_in[13];
  const float* bskip  = (const float*)d_in[14];
  const float* Wbeta  = (const float*)d_in[15];
  const float* W1     = (const float*)d_in[16];
  const float* b1     = (const float*)d_in[17];
  const float* g1     = (const float*)d_in[18];
  const float* be1    = (const float*)d_in[19];
  const float* W2     = (const float*)d_in[20];
  const float* b2     = (const float*)d_in[21];
  const float* predW  = (const float*)d_in[22];
  const float* predb  = (const float*)d_in[23];

  // ---- workspace layout (aliased lifetimes) ----
  float* ws = (float*)d_ws;
  size_t o = 0;
  auto alloc_f = [&](size_t n) { float* p = ws + o; o += n; return p; };
  float* A32   = alloc_f((size_t)N_ * 512);   // zf -> vpart[4][N][128] -> t1
  float* B32   = alloc_f((size_t)N_ * H_);    // h32
  float* xr    = alloc_f((size_t)N_ * H_);
  float* fpart = alloc_f((size_t)4 * N_ * H_);// FFN2 split-K partials
  float* stats = alloc_f(2 * 128 * DFF_);
  float* a_c   = alloc_f(DFF_);
  float* c_c   = alloc_f(DFF_);
  float* bcat  = alloc_f(5 * NF1_);
  float* bvm   = alloc_f(5 * 128);
  bf16* bp = (bf16*)(ws + o);
  size_t ob = 0;
  auto alloc_b = [&](size_t n) { bf16* p = bp + ob; ob += n; return p; };
  bf16* aggB = alloc_b((size_t)N_ * 512);
  bf16* hb   = alloc_b((size_t)N_ * H_);
  bf16* gated= alloc_b((size_t)N_ * H_);
  bf16* Wcat1= alloc_b((size_t)5 * WCAT1SZ);
  bf16* W1t  = alloc_b((size_t)5 * W1TSZ);
  bf16* W2t  = alloc_b((size_t)5 * W2TSZ);
  bf16* Wvs  = alloc_b((size_t)5 * WVSSZ);
  int* deg    = (int*)(bp + ob);
  int* offs   = deg + N_;
  int* cursor = offs + N_ + 1;
  int* srcs   = cursor + N_;
  int* bsum   = srcs + E_;       // 64

  float* zf   = A32;  float* t1 = A32;  float* vpart = A32;
  float* h32 = B32;

  // ---- weight prep ----
  k_ptrans<<<TRBLKS + 15, 256, 0, stream>>>(Wskip, W1, W2, bskip, bv,
                                            Wcat1, W1t, W2t, bcat, bvm);
  k_wvprep<<<320, 256, 0, stream>>>(Wv, Wvs);
  k_gmat<<<dim3(20, 2), 256, 0, stream>>>(Wq, Wk, bq, Wcat1, bcat);

  // ---- CSR build ----
  hipMemsetAsync(deg, 0, N_ * sizeof(int), stream);
  hipMemsetAsync(cursor, 0, N_ * sizeof(int), stream);
  k_count  <<<E_ / 256, 256, 0, stream>>>(edst, deg);
  k_bsum   <<<64, 256, 0, stream>>>(deg, bsum);
  k_boffs  <<<64, 256, 0, stream>>>(deg, bsum, offs);
  k_scatter<<<E_ / 256, 256, 0, stream>>>(esrc, edst, offs, cursor, srcs);

  // ---- embedding (+fused stats) + BN + GELU -> bf16 ----
  k_embed2<<<128, 256, 0, stream>>>(x, embW, embb, A32, stats, stats + 128 * 128);
  k_bn_finalize<128><<<1, 128, 0, stream>>>(stats, stats + 128 * 128, emb_g, emb_be, a_c, c_c);
  k_bn_apply_gelu_cast<128><<<N_ * H_ / 1024, 256, 0, stream>>>(A32, a_c, c_c, hb);

  for (int l = 0; l < L_; ++l) {
    const float* Wb_ = Wbeta + (size_t)l * 3 * H_;
    const float* b1_ = b1 + (size_t)l * DFF_;
    const float* g1_ = g1 + (size_t)l * DFF_;
    const float* be1_= be1 + (size_t)l * DFF_;
    const float* b2_ = b2 + (size_t)l * H_;

    // GEMM1: z | xr  (NOUT = 640)
    k_mfma<128, 128, NF1_, 128, 2><<<dim3(N_ / 128, NF1_ / 128), 256, 0, stream>>>(
        hb, nullptr, Wcat1 + (size_t)l * WCAT1SZ, bcat + (size_t)l * NF1_,
        nullptr, nullptr, zf, xr, nullptr, nullptr, nullptr, nullptr);

    k_attn<<<N_ / 4, 256, 0, stream>>>(zf, hb, srcs, offs, aggB);

    // Vproj split-K=4: partials into vpart (= A32, zf dead after attn)
    k_mfma<128, 512, 128, 64, 5><<<dim3(N_ / 64, 4), 256, 0, stream>>>(
        aggB, nullptr, Wvs + (size_t)l * WVSSZ, nullptr,
        vpart, nullptr, nullptr, nullptr, nullptr, nullptr, nullptr, nullptr);

    k_vredbeta<<<N_ / 4, 256, 0, stream>>>(vpart, xr, Wb_, bvm + (size_t)l * 128, offs, gated);

    // FFN1: fp32 out + fused BN partial stats (t1 overwrites vpart)
    k_mfma<128, 128, 512, 128, 3><<<dim3(N_ / 128, 4), 256, 0, stream>>>(
        gated, nullptr, W1t + (size_t)l * W1TSZ, b1_, t1, nullptr, nullptr, nullptr,
        stats, stats + 128 * 512, nullptr, nullptr);

    k_bn_finalize<512><<<4, 128, 0, stream>>>(stats, stats + 128 * 512, g1_, be1_, a_c, c_c);

    // FFN2 split-K=4: BN+GELU fused staging; partials into fpart
    k_mfma<128, 512, 128, 64, 4><<<dim3(N_ / 64, 4), 256, 0, stream>>>(
        nullptr, t1, W2t + (size_t)l * W2TSZ, nullptr, fpart, nullptr, nullptr, nullptr,
        nullptr, nullptr, a_c, c_c);

    k_f2red<<<N_ * H_ / 1024, 256, 0, stream>>>(fpart, b2_, h32, hb);
  }

  // ---- fused pooling + prediction ----
  k_poolpred<<<G_, 256, 0, stream>>>(h32, batch, predW, predb, (float*)d_out);
}